// Round 1
// baseline (733.584 us; speedup 1.0000x reference)
//
#include <hip/hip_runtime.h>

#define D 64
#define NB 64
#define NCHUNK 8
#define ZINV 0.125f
#define EPS 1e-5f

// ---------------------------------------------------------------------------
// Layout conventions:
//  - 256 threads/block; thread group = 4 consecutive lanes (same wave).
//  - group index g = tid>>2 (0..63), sub-lane q = tid&3 owning 16 of 64 dims.
//  - All LDS tiles use row stride 68 floats (272 B: 16B-aligned rows, bank
//    offset 4/row -> worst accesses are 2-way, which is free on CDNA4).
// ---------------------------------------------------------------------------

__device__ __forceinline__ void ln64(const float h[16], const float* __restrict__ g,
                                     const float* __restrict__ bt, int d0, float out[16]) {
  float s1 = 0.f;
#pragma unroll
  for (int i = 0; i < 16; ++i) s1 += h[i];
  s1 += __shfl_xor(s1, 1);
  s1 += __shfl_xor(s1, 2);
  float mean = s1 * 0.015625f;
  float s2 = 0.f;
#pragma unroll
  for (int i = 0; i < 16; ++i) { float c = h[i] - mean; s2 += c * c; }
  s2 += __shfl_xor(s2, 1);
  s2 += __shfl_xor(s2, 2);
  float rs = rsqrtf(s2 * 0.015625f + EPS);
#pragma unroll
  for (int i = 0; i < 16; ++i) out[i] = (h[i] - mean) * rs * g[d0 + i] + bt[d0 + i];
}

// ---------------------------------------------------------------------------
// Setup: segment offsets + QK0 = (I @ WQ0^T @ WK0) / Z   [64 x 64]
// ---------------------------------------------------------------------------
__global__ __launch_bounds__(256) void k_setup(const int* __restrict__ xlens,
                                               const float* __restrict__ I,
                                               const float* __restrict__ WQ0,
                                               const float* __restrict__ WK0,
                                               int* __restrict__ off,
                                               float* __restrict__ QK0) {
  int tid = threadIdx.x;
  if (tid == 0) {
    int s = 0;
    off[0] = 0;
    for (int b = 0; b < NB; ++b) { s += xlens[b]; off[b + 1] = s; }
  }
  __shared__ float qq0[64][68];
  int m = tid >> 2, q = tid & 3, e0 = q << 4;
  // qq0[m][a] = sum_d I[m][d] * WQ0[a][d]
#pragma unroll
  for (int i = 0; i < 16; ++i) {
    int a = e0 + i;
    float acc = 0.f;
    for (int d = 0; d < 64; ++d) acc += I[m * 64 + d] * WQ0[a * 64 + d];
    qq0[m][a] = acc;
  }
  // row m written/read by the same 4-lane group (same wave) -> no barrier needed
#pragma unroll
  for (int i = 0; i < 16; ++i) {
    int e = e0 + i;
    float acc = 0.f;
    for (int a = 0; a < 64; ++a) acc += qq0[m][a] * WK0[a * 64 + e];
    QK0[m * 64 + e] = acc * ZINV;
  }
}

// ---------------------------------------------------------------------------
// Phase A partials: per (segment, chunk): online softmax of 64 inducing-point
// queries over the chunk's tokens, accumulating weighted-x (WV0 folded later).
// ---------------------------------------------------------------------------
__global__ __launch_bounds__(256) void k_phaseA(const float* __restrict__ x,
                                                const int* __restrict__ off,
                                                const float* __restrict__ QK0,
                                                float* __restrict__ part_mx,
                                                float* __restrict__ part_sm,
                                                float* __restrict__ part_ax) {
  int b = blockIdx.x / NCHUNK, chunk = blockIdx.x % NCHUNK;
  int s0 = off[b], L = off[b + 1] - s0;
  int clen = (L + NCHUNK - 1) / NCHUNK;
  int t0 = chunk * clen;
  int t1 = t0 + clen; if (t1 > L) t1 = L;

  int tid = threadIdx.x;
  int wave = tid >> 6, lane = tid & 63;
  int mloc = lane >> 2, dq = lane & 3, e0 = dq << 4;
  int m = wave * 16 + mloc;  // query index 0..63

  __shared__ float xs[64][68];
  __shared__ float sc[4][16][68];

  float qk[16];
#pragma unroll
  for (int i = 0; i < 16; ++i) qk[i] = QK0[m * 64 + e0 + i];

  float mx = -1e30f, sm = 0.f;
  float acc[16];
#pragma unroll
  for (int i = 0; i < 16; ++i) acc[i] = 0.f;

  int ldr = tid >> 2, ldc = (tid & 3) << 4;

  for (int tt = t0; tt < t1; tt += 64) {
    int nt = t1 - tt; if (nt > 64) nt = 64;
    __syncthreads();  // protect xs from previous iteration's readers
    if (ldr < nt) {
      const float4* src = (const float4*)(x + ((size_t)(s0 + tt + ldr) << 6) + ldc);
      float4* dst = (float4*)&xs[ldr][ldc];
#pragma unroll
      for (int qd = 0; qd < 4; ++qd) dst[qd] = src[qd];
    }
    __syncthreads();

    // pass 1: scores s[m][t] = QK0[m] . x_t  (e-split + 4-lane butterfly)
    float tmax = -1e30f;
    for (int t = 0; t < nt; ++t) {
      float p = 0.f;
#pragma unroll
      for (int i = 0; i < 16; ++i) p += qk[i] * xs[t][e0 + i];
      p += __shfl_xor(p, 1);
      p += __shfl_xor(p, 2);
      tmax = fmaxf(tmax, p);              // every lane sees every t
      if (dq == (t & 3)) sc[wave][mloc][t] = p;  // single writer per score
    }

    float nm = fmaxf(mx, tmax);
    float f = __expf(mx - nm);  // first tile: exp(-inf) = 0
    sm *= f;
#pragma unroll
    for (int i = 0; i < 16; ++i) acc[i] *= f;
    mx = nm;

    // pass 2: accumulate weighted x
    float psum = 0.f;
    for (int t = 0; t < nt; ++t) {
      float p = __expf(sc[wave][mloc][t] - mx);
      psum += p;
#pragma unroll
      for (int i = 0; i < 16; ++i) acc[i] += p * xs[t][e0 + i];
    }
    sm += psum;
  }

  int base = (b * NCHUNK + chunk) * 64 + m;
  if (dq == 0) { part_mx[base] = mx; part_sm[base] = sm; }
#pragma unroll
  for (int i = 0; i < 16; ++i) part_ax[(size_t)base * 64 + e0 + i] = acc[i];
}

// ---------------------------------------------------------------------------
// Combine: merge chunk partials -> apply WV0 -> LN -> FC -> LN -> i_seg;
// then build K1f = WQ1^T WK1 i_seg / Z and V1 = i_seg WV1^T (per segment).
// ---------------------------------------------------------------------------
__global__ __launch_bounds__(256) void k_combine(const float* __restrict__ part_mx,
                                                 const float* __restrict__ part_sm,
                                                 const float* __restrict__ part_ax,
                                                 const float* __restrict__ I,
                                                 const float* __restrict__ WV0,
                                                 const float* __restrict__ FCw0,
                                                 const float* __restrict__ FCb0,
                                                 const float* __restrict__ g00,
                                                 const float* __restrict__ b00,
                                                 const float* __restrict__ g01,
                                                 const float* __restrict__ b01,
                                                 const float* __restrict__ WK1,
                                                 const float* __restrict__ WQ1,
                                                 const float* __restrict__ WV1,
                                                 float* __restrict__ K1f,
                                                 float* __restrict__ V1) {
  int b = blockIdx.x;
  int tid = threadIdx.x;
  int m = tid >> 2, dq = tid & 3, e0 = dq << 4;

  __shared__ float axs[64][68];
  __shared__ float hhs[64][68];

  float Mx = -1e30f;
#pragma unroll
  for (int c = 0; c < NCHUNK; ++c)
    Mx = fmaxf(Mx, part_mx[(b * NCHUNK + c) * 64 + m]);
  float S = 0.f;
  float ax[16];
#pragma unroll
  for (int i = 0; i < 16; ++i) ax[i] = 0.f;
  for (int c = 0; c < NCHUNK; ++c) {
    int pb = (b * NCHUNK + c) * 64 + m;
    float f = __expf(part_mx[pb] - Mx);
    S += part_sm[pb] * f;
#pragma unroll
    for (int i = 0; i < 16; ++i) ax[i] += part_ax[(size_t)pb * 64 + e0 + i] * f;
  }
  float invS = 1.f / S;
#pragma unroll
  for (int i = 0; i < 16; ++i) axs[m][e0 + i] = ax[i] * invS;

  // av[d] = sum_e axs[m][e] * WV0[d][e];  h = I[m] + av ; LN(g00,b00)
  float h[16], hh[16];
#pragma unroll
  for (int i = 0; i < 16; ++i) {
    int d = e0 + i;
    float a = 0.f;
    for (int e = 0; e < 64; ++e) a += axs[m][e] * WV0[d * 64 + e];
    h[i] = I[m * 64 + d] + a;
  }
  ln64(h, g00, b00, e0, hh);
#pragma unroll
  for (int i = 0; i < 16; ++i) hhs[m][e0 + i] = hh[i];

  // FC + relu + residual, LN(g01,b01) -> i_seg (kept in axs row m)
  float u[16];
#pragma unroll
  for (int i = 0; i < 16; ++i) {
    int d = e0 + i;
    float a = FCb0[d];
    for (int e = 0; e < 64; ++e) a += hhs[m][e] * FCw0[d * 64 + e];
    u[i] = hh[i] + fmaxf(a, 0.f);
  }
  float iseg[16];
  ln64(u, g01, b01, e0, iseg);
#pragma unroll
  for (int i = 0; i < 16; ++i) axs[m][e0 + i] = iseg[i];

  // tmp[a] = sum_d i_seg[m][d] * WK1[a][d]   (into hhs row m)
#pragma unroll
  for (int i = 0; i < 16; ++i) {
    int a = e0 + i;
    float t = 0.f;
    for (int d = 0; d < 64; ++d) t += axs[m][d] * WK1[a * 64 + d];
    hhs[m][a] = t;
  }
  // K1f[b][m][e] = (1/Z) * sum_a tmp[a] * WQ1[a][e]
#pragma unroll
  for (int i = 0; i < 16; ++i) {
    int e = e0 + i;
    float t = 0.f;
    for (int a = 0; a < 64; ++a) t += hhs[m][a] * WQ1[a * 64 + e];
    K1f[((size_t)(b * 64 + m) << 6) + e] = t * ZINV;
  }
  // V1[b][m][d] = sum_e i_seg[m][e] * WV1[d][e]
#pragma unroll
  for (int i = 0; i < 16; ++i) {
    int d = e0 + i;
    float t = 0.f;
    for (int e = 0; e < 64; ++e) t += axs[m][e] * WV1[d * 64 + e];
    V1[((size_t)(b * 64 + m) << 6) + d] = t;
  }
}

// ---------------------------------------------------------------------------
// Phase B: per token: softmax(x_t . K1f[b]) @ V1[b] -> LN -> FC -> LN -> out
// ---------------------------------------------------------------------------
__global__ __launch_bounds__(256) void k_phaseB(const float* __restrict__ x,
                                                const int* __restrict__ off,
                                                const float* __restrict__ K1f,
                                                const float* __restrict__ V1,
                                                const float* __restrict__ FCw1,
                                                const float* __restrict__ FCb1,
                                                const float* __restrict__ g10,
                                                const float* __restrict__ b10,
                                                const float* __restrict__ g11,
                                                const float* __restrict__ b11,
                                                float* __restrict__ outp) {
  int b = blockIdx.x >> 6, tile = blockIdx.x & 63;
  int s0 = off[b], L = off[b + 1] - s0;
  int t0 = tile << 6;
  if (t0 >= L) return;
  int nt = L - t0; if (nt > 64) nt = 64;

  __shared__ float xs[64][68];   // x tile; later reused for p then hh (row-private)
  __shared__ float ks[64][68];
  __shared__ float vsl[64][68];

  int tid = threadIdx.x;
  int ldr = tid >> 2, ldc = (tid & 3) << 4;
  {
    const float4* sk = (const float4*)(K1f + ((size_t)(b * 64 + ldr) << 6) + ldc);
    float4* dk = (float4*)&ks[ldr][ldc];
#pragma unroll
    for (int q = 0; q < 4; ++q) dk[q] = sk[q];
    const float4* sv = (const float4*)(V1 + ((size_t)(b * 64 + ldr) << 6) + ldc);
    float4* dv = (float4*)&vsl[ldr][ldc];
#pragma unroll
    for (int q = 0; q < 4; ++q) dv[q] = sv[q];
    if (ldr < nt) {
      const float4* sx = (const float4*)(x + ((size_t)(s0 + t0 + ldr) << 6) + ldc);
      float4* dx = (float4*)&xs[ldr][ldc];
#pragma unroll
      for (int q = 0; q < 4; ++q) dx[q] = sx[q];
    }
  }
  __syncthreads();

  int t = tid >> 2, part = tid & 3, d0 = part << 4;
  if (t >= nt) return;  // no barriers below; whole 4-lane groups exit together

  float xr[16];
#pragma unroll
  for (int i = 0; i < 16; ++i) xr[i] = xs[t][d0 + i];

  // scores: e-split partial dots + 4-lane butterfly; each lane keeps j = 4*jj+part
  float sreg[16];
  float smax = -1e30f;
#pragma unroll
  for (int jj = 0; jj < 16; ++jj) {
#pragma unroll
    for (int jq = 0; jq < 4; ++jq) {
      int j = jj * 4 + jq;
      float p = 0.f;
#pragma unroll
      for (int i = 0; i < 16; ++i) p += xr[i] * ks[j][d0 + i];
      p += __shfl_xor(p, 1);
      p += __shfl_xor(p, 2);
      smax = fmaxf(smax, p);
      if (jq == part) sreg[jj] = p;
    }
  }
  float psum = 0.f;
#pragma unroll
  for (int jj = 0; jj < 16; ++jj) {
    float p = __expf(sreg[jj] - smax);
    sreg[jj] = p;
    psum += p;
  }
  psum += __shfl_xor(psum, 1);
  psum += __shfl_xor(psum, 2);
  float inv = 1.f / psum;
#pragma unroll
  for (int jj = 0; jj < 16; ++jj) xs[t][jj * 4 + part] = sreg[jj] * inv;  // p into (dead) x row

  // av[d] = sum_j p[j] * V1[j][d]
  float av[16];
#pragma unroll
  for (int i = 0; i < 16; ++i) av[i] = 0.f;
  for (int j = 0; j < 64; ++j) {
    float p = xs[t][j];
#pragma unroll
    for (int i = 0; i < 16; ++i) av[i] += p * vsl[j][d0 + i];
  }

  float h[16], hh[16];
#pragma unroll
  for (int i = 0; i < 16; ++i) h[i] = xr[i] + av[i];
  ln64(h, g10, b10, d0, hh);
#pragma unroll
  for (int i = 0; i < 16; ++i) xs[t][d0 + i] = hh[i];  // hh into row (p consumed)

  float u[16];
#pragma unroll
  for (int i = 0; i < 16; ++i) {
    int d = d0 + i;
    float a = FCb1[d];
    for (int e = 0; e < 64; ++e) a += xs[t][e] * FCw1[d * 64 + e];
    u[i] = hh[i] + fmaxf(a, 0.f);
  }
  float o[16];
  ln64(u, g11, b11, d0, o);

  float4* dst = (float4*)(outp + ((size_t)(s0 + t0 + t) << 6) + d0);
#pragma unroll
  for (int q = 0; q < 4; ++q)
    dst[q] = make_float4(o[q * 4], o[q * 4 + 1], o[q * 4 + 2], o[q * 4 + 3]);
}

// ---------------------------------------------------------------------------

extern "C" void kernel_launch(void* const* d_in, const int* in_sizes, int n_in,
                              void* d_out, int out_size, void* d_ws, size_t ws_size,
                              hipStream_t stream) {
  const float* x    = (const float*)d_in[0];
  const int*   xlen = (const int*)d_in[1];
  const float* I    = (const float*)d_in[2];
  const float* WQ0  = (const float*)d_in[3];
  const float* WK0  = (const float*)d_in[4];
  const float* WV0  = (const float*)d_in[5];
  const float* FCw0 = (const float*)d_in[6];
  const float* FCb0 = (const float*)d_in[7];
  const float* g00  = (const float*)d_in[8];
  const float* b00  = (const float*)d_in[9];
  const float* g01  = (const float*)d_in[10];
  const float* b01  = (const float*)d_in[11];
  const float* WQ1  = (const float*)d_in[12];
  const float* WK1  = (const float*)d_in[13];
  const float* WV1  = (const float*)d_in[14];
  const float* FCw1 = (const float*)d_in[15];
  const float* FCb1 = (const float*)d_in[16];
  const float* g10  = (const float*)d_in[17];
  const float* b10  = (const float*)d_in[18];
  const float* g11  = (const float*)d_in[19];
  const float* b11  = (const float*)d_in[20];

  // workspace layout
  int* off = (int*)d_ws;                       // 65 ints (padded to 512 B)
  float* fb  = (float*)((char*)d_ws + 512);
  float* QK0 = fb;                             // 4096
  float* pmx = QK0 + 4096;                     // 64*8*64   = 32768
  float* psm = pmx + NB * NCHUNK * 64;         // 32768
  float* pax = psm + NB * NCHUNK * 64;         // 64*8*64*64 = 2097152
  float* K1f = pax + (size_t)NB * NCHUNK * 64 * 64;  // 262144
  float* V1  = K1f + NB * 64 * 64;             // 262144

  k_setup<<<1, 256, 0, stream>>>(xlen, I, WQ0, WK0, off, QK0);
  k_phaseA<<<NB * NCHUNK, 256, 0, stream>>>(x, off, QK0, pmx, psm, pax);
  k_combine<<<NB, 256, 0, stream>>>(pmx, psm, pax, I, WV0, FCw0, FCb0,
                                    g00, b00, g01, b01, WK1, WQ1, WV1, K1f, V1);
  k_phaseB<<<NB * 64, 256, 0, stream>>>(x, off, K1f, V1, FCw1, FCb1,
                                        g10, b10, g11, b11, (float*)d_out);
}

// Round 2
// 267.912 us; speedup vs baseline: 2.7381x; 2.7381x over previous
//
#include <hip/hip_runtime.h>

#define NB 64
#define NCHUNK 8
#define ZINV 0.125f
#define EPS 1e-5f

typedef __attribute__((ext_vector_type(8))) short short8;
typedef __attribute__((ext_vector_type(4))) float f32x4;
typedef unsigned short ushort_t;

__device__ __forceinline__ f32x4 mm(short8 a, short8 b, f32x4 c) {
  return __builtin_amdgcn_mfma_f32_16x16x32_bf16(a, b, c, 0, 0, 0);
}
__device__ __forceinline__ ushort_t f2bf(float f) {
  unsigned u = __float_as_uint(f);
  u += 0x7fffu + ((u >> 16) & 1u);
  return (ushort_t)(u >> 16);
}
__device__ __forceinline__ unsigned pack2(float a, float b) {
  return (unsigned)f2bf(a) | ((unsigned)f2bf(b) << 16);
}
__device__ __forceinline__ float bf2f(ushort_t h) {
  return __uint_as_float(((unsigned)h) << 16);
}

// ---------------------------------------------------------------------------
// Setup: offsets, QK0bf = bf16((I WQ0^T WK0)/Z), Wfcbf = bf16(FCw1)
// ---------------------------------------------------------------------------
__global__ __launch_bounds__(256) void k_setup(const int* __restrict__ xlens,
                                               const float* __restrict__ I,
                                               const float* __restrict__ WQ0,
                                               const float* __restrict__ WK0,
                                               const float* __restrict__ FCw1,
                                               int* __restrict__ off,
                                               ushort_t* __restrict__ QK0bf,
                                               ushort_t* __restrict__ Wfcbf) {
  int tid = threadIdx.x;
  if (tid == 0) {
    int s = 0;
    off[0] = 0;
    for (int b = 0; b < NB; ++b) { s += xlens[b]; off[b + 1] = s; }
  }
  __shared__ float qq0[64][68];
  int m = tid >> 2, q = tid & 3, e0 = q << 4;
#pragma unroll
  for (int i = 0; i < 16; ++i) {
    int a = e0 + i;
    float acc = 0.f;
    for (int d = 0; d < 64; ++d) acc += I[m * 64 + d] * WQ0[a * 64 + d];
    qq0[m][a] = acc;
  }
  // row m written/read by same 4-lane group (same wave) -> no barrier
#pragma unroll
  for (int i = 0; i < 16; ++i) {
    int e = e0 + i;
    float acc = 0.f;
    for (int a = 0; a < 64; ++a) acc += qq0[m][a] * WK0[a * 64 + e];
    QK0bf[m * 64 + e] = f2bf(acc * ZINV);
  }
#pragma unroll
  for (int i = 0; i < 16; ++i)
    Wfcbf[m * 64 + e0 + i] = f2bf(FCw1[m * 64 + e0 + i]);
}

// ---------------------------------------------------------------------------
// Phase A: per (segment, chunk) MFMA flash-attention partials.
// GEMM1: S^T[t][m] = x[t][:] . QK0[m][:]     (A=xbf row-major, B=QK0bf)
// GEMM2: acc[m][e] += P[m][t] * x[t][e]      (A=pbf[m][t],  B=xT[e][t])
// ---------------------------------------------------------------------------
__global__ __launch_bounds__(256) void k_phaseA(const float* __restrict__ x,
                                                const int* __restrict__ off,
                                                const ushort_t* __restrict__ QK0bf,
                                                float* __restrict__ part_mx,
                                                float* __restrict__ part_sm,
                                                float* __restrict__ part_ax) {
  int b = blockIdx.x / NCHUNK, chunk = blockIdx.x % NCHUNK;
  int s0 = off[b], L = off[b + 1] - s0;
  int clen = (L + NCHUNK - 1) / NCHUNK;
  int t0 = chunk * clen;
  int t1 = t0 + clen; if (t1 > L) t1 = L;

  __shared__ ushort_t xbf[64][72];  // x tile, [t][e] bf16
  __shared__ ushort_t xT[64][72];   // x tile transposed, [e][t] bf16
  __shared__ ushort_t pbf[64][72];  // P, [m][t] bf16
  __shared__ float S[64][68];       // raw scores [m][t]
  __shared__ float pm[4][64];       // per-wave col max
  __shared__ float ps[4][64];       // per-wave col sum

  int tid = threadIdx.x;
  int w = tid >> 6, l = tid & 63, l15 = l & 15, lh = l >> 4;
  int srow = tid >> 2, sc0 = (tid & 3) << 4;

  // hoisted B-frags for GEMM1 (QK0, shared across all tiles; L1-resident)
  short8 bq[4][2];
#pragma unroll
  for (int n = 0; n < 4; ++n)
#pragma unroll
    for (int kt = 0; kt < 2; ++kt)
      bq[n][kt] = *(const short8*)(QK0bf + ((16 * n + l15) << 6) + kt * 32 + lh * 8);

  float mx = -1e30f, sm = 0.f;
  f32x4 acc[4];
#pragma unroll
  for (int n = 0; n < 4; ++n) acc[n] = (f32x4){0.f, 0.f, 0.f, 0.f};

  for (int tt = t0; tt < t1; tt += 64) {
    __syncthreads();  // B0: protect LDS from previous iteration's readers
    // ---- stage x tile (row-major bf16 + transposed bf16) ----
    {
      int g = tt + srow;
      unsigned* dst = (unsigned*)&xbf[srow][sc0];
      if (g < t1) {
        const float4* src = (const float4*)(x + ((size_t)(s0 + g) << 6) + sc0);
        float4 A0 = src[0], A1 = src[1], A2 = src[2], A3 = src[3];
        float vv[16] = {A0.x, A0.y, A0.z, A0.w, A1.x, A1.y, A1.z, A1.w,
                        A2.x, A2.y, A2.z, A2.w, A3.x, A3.y, A3.z, A3.w};
        dst[0] = pack2(vv[0], vv[1]);   dst[1] = pack2(vv[2], vv[3]);
        dst[2] = pack2(vv[4], vv[5]);   dst[3] = pack2(vv[6], vv[7]);
        dst[4] = pack2(vv[8], vv[9]);   dst[5] = pack2(vv[10], vv[11]);
        dst[6] = pack2(vv[12], vv[13]); dst[7] = pack2(vv[14], vv[15]);
#pragma unroll
        for (int i = 0; i < 16; ++i) xT[sc0 + i][srow] = f2bf(vv[i]);
      } else {
#pragma unroll
        for (int i = 0; i < 8; ++i) dst[i] = 0u;
#pragma unroll
        for (int i = 0; i < 16; ++i) xT[sc0 + i][srow] = 0;
      }
    }
    // ---- GEMM1 (own-wave rows of xbf; same-wave LDS ordering) ----
    short8 a0 = *(const short8*)&xbf[16 * w + l15][lh * 8];
    short8 a1 = *(const short8*)&xbf[16 * w + l15][32 + lh * 8];
    f32x4 c1[4];
#pragma unroll
    for (int n = 0; n < 4; ++n) {
      c1[n] = mm(a0, bq[n][0], (f32x4){0.f, 0.f, 0.f, 0.f});
      c1[n] = mm(a1, bq[n][1], c1[n]);
    }
    // ---- write raw scores with tail masking: S[m][t] ----
#pragma unroll
    for (int n = 0; n < 4; ++n)
#pragma unroll
      for (int r = 0; r < 4; ++r) {
        int tl = 16 * w + 4 * lh + r;
        S[16 * n + l15][tl] = (tt + tl < t1) ? c1[n][r] : -1e30f;
      }
    // ---- local max over this wave's 16 cols (same-wave S rows) ----
    float sv[16];
    float lmax = -1e30f;
#pragma unroll
    for (int i = 0; i < 16; ++i) { sv[i] = S[l][16 * w + i]; lmax = fmaxf(lmax, sv[i]); }
    pm[w][l] = lmax;
    __syncthreads();  // B1
    float tmax = fmaxf(fmaxf(pm[0][l], pm[1][l]), fmaxf(pm[2][l], pm[3][l]));
    float nm = fmaxf(mx, tmax);
    float f = __expf(mx - nm);
    mx = nm;
    float psum = 0.f;
    float pv[16];
#pragma unroll
    for (int i = 0; i < 16; ++i) { pv[i] = __expf(sv[i] - nm); psum += pv[i]; }
    {
      unsigned* prow = (unsigned*)&pbf[l][16 * w];
#pragma unroll
      for (int i = 0; i < 8; ++i) prow[i] = pack2(pv[2 * i], pv[2 * i + 1]);
    }
    ps[w][l] = psum;
    __syncthreads();  // B2
    sm = sm * f + ps[0][l] + ps[1][l] + ps[2][l] + ps[3][l];
    // ---- rescale acc, then GEMM2 accumulate ----
    float fv[4];
#pragma unroll
    for (int r = 0; r < 4; ++r) fv[r] = __shfl(f, 16 * w + 4 * lh + r);
#pragma unroll
    for (int n = 0; n < 4; ++n)
#pragma unroll
      for (int r = 0; r < 4; ++r) acc[n][r] *= fv[r];
    short8 pa0 = *(const short8*)&pbf[16 * w + l15][lh * 8];
    short8 pa1 = *(const short8*)&pbf[16 * w + l15][32 + lh * 8];
#pragma unroll
    for (int n = 0; n < 4; ++n) {
      short8 bx0 = *(const short8*)&xT[16 * n + l15][lh * 8];
      short8 bx1 = *(const short8*)&xT[16 * n + l15][32 + lh * 8];
      acc[n] = mm(pa0, bx0, acc[n]);
      acc[n] = mm(pa1, bx1, acc[n]);
    }
  }
  // ---- epilogue: partial state ----
  int base = (b * NCHUNK + chunk) * 64;
  if (w == 0) { part_mx[base + l] = mx; part_sm[base + l] = sm; }
#pragma unroll
  for (int n = 0; n < 4; ++n)
#pragma unroll
    for (int r = 0; r < 4; ++r) {
      int m = 16 * w + 4 * lh + r;
      part_ax[((size_t)(base + m) << 6) + 16 * n + l15] = acc[n][r];
    }
}

// ---------------------------------------------------------------------------
// Combine: merge partials -> WV0 -> LN -> FC -> LN -> i_seg -> K1fbf, V1Tbf
// ---------------------------------------------------------------------------
__device__ __forceinline__ void ln64(const float h[16], const float* __restrict__ g,
                                     const float* __restrict__ bt, int d0, float out[16]) {
  float s1 = 0.f;
#pragma unroll
  for (int i = 0; i < 16; ++i) s1 += h[i];
  s1 += __shfl_xor(s1, 1);
  s1 += __shfl_xor(s1, 2);
  float mean = s1 * 0.015625f;
  float s2 = 0.f;
#pragma unroll
  for (int i = 0; i < 16; ++i) { float c = h[i] - mean; s2 += c * c; }
  s2 += __shfl_xor(s2, 1);
  s2 += __shfl_xor(s2, 2);
  float rs = rsqrtf(s2 * 0.015625f + EPS);
#pragma unroll
  for (int i = 0; i < 16; ++i) out[i] = (h[i] - mean) * rs * g[d0 + i] + bt[d0 + i];
}

__global__ __launch_bounds__(256) void k_combine(const float* __restrict__ part_mx,
                                                 const float* __restrict__ part_sm,
                                                 const float* __restrict__ part_ax,
                                                 const float* __restrict__ I,
                                                 const float* __restrict__ WV0,
                                                 const float* __restrict__ FCw0,
                                                 const float* __restrict__ FCb0,
                                                 const float* __restrict__ g00,
                                                 const float* __restrict__ b00,
                                                 const float* __restrict__ g01,
                                                 const float* __restrict__ b01,
                                                 const float* __restrict__ WK1,
                                                 const float* __restrict__ WQ1,
                                                 const float* __restrict__ WV1,
                                                 ushort_t* __restrict__ K1fbf,
                                                 ushort_t* __restrict__ V1Tbf) {
  int b = blockIdx.x;
  int tid = threadIdx.x;
  int m = tid >> 2, dq = tid & 3, e0 = dq << 4;

  __shared__ float axs[64][68];
  __shared__ float hhs[64][68];

  float Mx = -1e30f;
#pragma unroll
  for (int c = 0; c < NCHUNK; ++c)
    Mx = fmaxf(Mx, part_mx[(b * NCHUNK + c) * 64 + m]);
  float S = 0.f;
  float ax[16];
#pragma unroll
  for (int i = 0; i < 16; ++i) ax[i] = 0.f;
  for (int c = 0; c < NCHUNK; ++c) {
    int pb = (b * NCHUNK + c) * 64 + m;
    float f = __expf(part_mx[pb] - Mx);
    S += part_sm[pb] * f;
#pragma unroll
    for (int i = 0; i < 16; ++i) ax[i] += part_ax[((size_t)pb << 6) + e0 + i] * f;
  }
  float invS = 1.f / S;
#pragma unroll
  for (int i = 0; i < 16; ++i) axs[m][e0 + i] = ax[i] * invS;

  float h[16], hh[16];
#pragma unroll
  for (int i = 0; i < 16; ++i) {
    int d = e0 + i;
    float a = 0.f;
    for (int e = 0; e < 64; ++e) a += axs[m][e] * WV0[d * 64 + e];
    h[i] = I[m * 64 + d] + a;
  }
  ln64(h, g00, b00, e0, hh);
#pragma unroll
  for (int i = 0; i < 16; ++i) hhs[m][e0 + i] = hh[i];

  float u[16];
#pragma unroll
  for (int i = 0; i < 16; ++i) {
    int d = e0 + i;
    float a = FCb0[d];
    for (int e = 0; e < 64; ++e) a += hhs[m][e] * FCw0[d * 64 + e];
    u[i] = hh[i] + fmaxf(a, 0.f);
  }
  float iseg[16];
  ln64(u, g01, b01, e0, iseg);
#pragma unroll
  for (int i = 0; i < 16; ++i) axs[m][e0 + i] = iseg[i];

#pragma unroll
  for (int i = 0; i < 16; ++i) {
    int a = e0 + i;
    float t = 0.f;
    for (int d = 0; d < 64; ++d) t += axs[m][d] * WK1[a * 64 + d];
    hhs[m][a] = t;
  }
#pragma unroll
  for (int i = 0; i < 16; ++i) {
    int e = e0 + i;
    float t = 0.f;
    for (int a = 0; a < 64; ++a) t += hhs[m][a] * WQ1[a * 64 + e];
    K1fbf[((size_t)(b * 64 + m) << 6) + e] = f2bf(t * ZINV);
  }
#pragma unroll
  for (int i = 0; i < 16; ++i) {
    int d = e0 + i;
    float t = 0.f;
    for (int e = 0; e < 64; ++e) t += axs[m][e] * WV1[d * 64 + e];
    V1Tbf[((size_t)(b * 64 + d) << 6) + m] = f2bf(t);  // transposed store [d][m]
  }
}

// ---------------------------------------------------------------------------
// Phase B: per 64-token tile, 3 chained per-wave MFMA GEMMs, zero barriers.
// GEMM1: S[t][j] = x[t][:] . K1f[j][:]     (A=xbf,      B=K1fbf global)
// GEMM2: AV[t][d] = P[t][:] . V1T[d][:]    (A=pbf,      B=V1Tbf global)
// GEMM3: U[t][dd] = H[t][:] . FCw1[dd][:]  (A=pbf(=H),  B=Wfcbf global)
// ---------------------------------------------------------------------------
__global__ __launch_bounds__(256) void k_phaseB(const float* __restrict__ x,
                                                const int* __restrict__ off,
                                                const ushort_t* __restrict__ K1fbf,
                                                const ushort_t* __restrict__ V1Tbf,
                                                const ushort_t* __restrict__ Wfcbf,
                                                const float* __restrict__ FCb1,
                                                const float* __restrict__ g10,
                                                const float* __restrict__ b10,
                                                const float* __restrict__ g11,
                                                const float* __restrict__ b11,
                                                float* __restrict__ outp) {
  int b = blockIdx.x >> 6, tile = blockIdx.x & 63;
  int s0 = off[b], L = off[b + 1] - s0;
  int t0 = tile << 6;
  if (t0 >= L) return;
  int nt = L - t0; if (nt > 64) nt = 64;

  __shared__ ushort_t xbf[64][72];
  __shared__ ushort_t pbf[64][72];

  int tid = threadIdx.x;
  int w = tid >> 6, l = tid & 63, l15 = l & 15, lh = l >> 4;
  int srow = tid >> 2, sc0 = (tid & 3) << 4;

  // ---- stage x tile bf16 (own-wave rows; no barrier needed) ----
  {
    unsigned* dst = (unsigned*)&xbf[srow][sc0];
    if (srow < nt) {
      const float4* src = (const float4*)(x + ((size_t)(s0 + t0 + srow) << 6) + sc0);
      float4 A0 = src[0], A1 = src[1], A2 = src[2], A3 = src[3];
      dst[0] = pack2(A0.x, A0.y); dst[1] = pack2(A0.z, A0.w);
      dst[2] = pack2(A1.x, A1.y); dst[3] = pack2(A1.z, A1.w);
      dst[4] = pack2(A2.x, A2.y); dst[5] = pack2(A2.z, A2.w);
      dst[6] = pack2(A3.x, A3.y); dst[7] = pack2(A3.z, A3.w);
    } else {
#pragma unroll
      for (int i = 0; i < 8; ++i) dst[i] = 0u;
    }
  }
  // per-lane epilogue params for d = 16n + l15
  float gg0[4], bb0[4], gg1[4], bb1[4], fb[4];
#pragma unroll
  for (int n = 0; n < 4; ++n) {
    int d = 16 * n + l15;
    gg0[n] = g10[d]; bb0[n] = b10[d];
    gg1[n] = g11[d]; bb1[n] = b11[d];
    fb[n] = FCb1[d];
  }
  // ---- GEMM1: scores ----
  short8 a0 = *(const short8*)&xbf[16 * w + l15][lh * 8];
  short8 a1 = *(const short8*)&xbf[16 * w + l15][32 + lh * 8];
  const ushort_t* Kb = K1fbf + ((size_t)b << 12);
  f32x4 c1[4];
#pragma unroll
  for (int n = 0; n < 4; ++n) {
    short8 bk0 = *(const short8*)(Kb + ((16 * n + l15) << 6) + lh * 8);
    short8 bk1 = *(const short8*)(Kb + ((16 * n + l15) << 6) + 32 + lh * 8);
    c1[n] = mm(a0, bk0, (f32x4){0.f, 0.f, 0.f, 0.f});
    c1[n] = mm(a1, bk1, c1[n]);
  }
  // ---- softmax per token row (n in-lane + 16 lanes) ----
  float inv[4];
#pragma unroll
  for (int r = 0; r < 4; ++r) {
    float mxr = fmaxf(fmaxf(c1[0][r], c1[1][r]), fmaxf(c1[2][r], c1[3][r]));
    mxr = fmaxf(mxr, __shfl_xor(mxr, 1));
    mxr = fmaxf(mxr, __shfl_xor(mxr, 2));
    mxr = fmaxf(mxr, __shfl_xor(mxr, 4));
    mxr = fmaxf(mxr, __shfl_xor(mxr, 8));
    float s = 0.f;
#pragma unroll
    for (int n = 0; n < 4; ++n) {
      float p = __expf(c1[n][r] - mxr);
      c1[n][r] = p;
      s += p;
    }
    s += __shfl_xor(s, 1);
    s += __shfl_xor(s, 2);
    s += __shfl_xor(s, 4);
    s += __shfl_xor(s, 8);
    inv[r] = 1.f / s;
  }
  // ---- P -> LDS bf16 (unnormalized; inv folded after GEMM2) ----
#pragma unroll
  for (int n = 0; n < 4; ++n)
#pragma unroll
    for (int r = 0; r < 4; ++r)
      pbf[16 * w + 4 * lh + r][16 * n + l15] = f2bf(c1[n][r]);
  // ---- GEMM2: P @ V1 ----
  short8 pa0 = *(const short8*)&pbf[16 * w + l15][lh * 8];
  short8 pa1 = *(const short8*)&pbf[16 * w + l15][32 + lh * 8];
  const ushort_t* Vb = V1Tbf + ((size_t)b << 12);
  f32x4 c2[4];
#pragma unroll
  for (int n = 0; n < 4; ++n) {
    short8 bv0 = *(const short8*)(Vb + ((16 * n + l15) << 6) + lh * 8);
    short8 bv1 = *(const short8*)(Vb + ((16 * n + l15) << 6) + 32 + lh * 8);
    c2[n] = mm(pa0, bv0, (f32x4){0.f, 0.f, 0.f, 0.f});
    c2[n] = mm(pa1, bv1, c2[n]);
  }
  // ---- residual + LN1 -> hh; hh -> pbf (bf16) ----
  float hh[4][4];
#pragma unroll
  for (int r = 0; r < 4; ++r) {
    int t = 16 * w + 4 * lh + r;
    float h[4];
#pragma unroll
    for (int n = 0; n < 4; ++n)
      h[n] = c2[n][r] * inv[r] + bf2f(xbf[t][16 * n + l15]);
    float s1 = h[0] + h[1] + h[2] + h[3];
    s1 += __shfl_xor(s1, 1); s1 += __shfl_xor(s1, 2);
    s1 += __shfl_xor(s1, 4); s1 += __shfl_xor(s1, 8);
    float mean = s1 * 0.015625f;
    float s2 = 0.f;
#pragma unroll
    for (int n = 0; n < 4; ++n) { float c = h[n] - mean; s2 += c * c; }
    s2 += __shfl_xor(s2, 1); s2 += __shfl_xor(s2, 2);
    s2 += __shfl_xor(s2, 4); s2 += __shfl_xor(s2, 8);
    float rs = rsqrtf(s2 * 0.015625f + EPS);
#pragma unroll
    for (int n = 0; n < 4; ++n) {
      hh[n][r] = (h[n] - mean) * rs * gg0[n] + bb0[n];
      pbf[t][16 * n + l15] = f2bf(hh[n][r]);
    }
  }
  // ---- GEMM3: H @ FCw1^T ----
  short8 ha0 = *(const short8*)&pbf[16 * w + l15][lh * 8];
  short8 ha1 = *(const short8*)&pbf[16 * w + l15][32 + lh * 8];
  f32x4 c3[4];
#pragma unroll
  for (int n = 0; n < 4; ++n) {
    short8 bw0 = *(const short8*)(Wfcbf + ((16 * n + l15) << 6) + lh * 8);
    short8 bw1 = *(const short8*)(Wfcbf + ((16 * n + l15) << 6) + 32 + lh * 8);
    c3[n] = mm(ha0, bw0, (f32x4){0.f, 0.f, 0.f, 0.f});
    c3[n] = mm(ha1, bw1, c3[n]);
  }
  // ---- relu + residual + LN2 + store ----
#pragma unroll
  for (int r = 0; r < 4; ++r) {
    int t = 16 * w + 4 * lh + r;
    float u[4];
#pragma unroll
    for (int n = 0; n < 4; ++n)
      u[n] = hh[n][r] + fmaxf(c3[n][r] + fb[n], 0.f);
    float s1 = u[0] + u[1] + u[2] + u[3];
    s1 += __shfl_xor(s1, 1); s1 += __shfl_xor(s1, 2);
    s1 += __shfl_xor(s1, 4); s1 += __shfl_xor(s1, 8);
    float mean = s1 * 0.015625f;
    float s2 = 0.f;
#pragma unroll
    for (int n = 0; n < 4; ++n) { float c = u[n] - mean; s2 += c * c; }
    s2 += __shfl_xor(s2, 1); s2 += __shfl_xor(s2, 2);
    s2 += __shfl_xor(s2, 4); s2 += __shfl_xor(s2, 8);
    float rs = rsqrtf(s2 * 0.015625f + EPS);
    if (t < nt) {
#pragma unroll
      for (int n = 0; n < 4; ++n)
        outp[((size_t)(s0 + t0 + t) << 6) + 16 * n + l15] =
            (u[n] - mean) * rs * gg1[n] + bb1[n];
    }
  }
}

// ---------------------------------------------------------------------------

extern "C" void kernel_launch(void* const* d_in, const int* in_sizes, int n_in,
                              void* d_out, int out_size, void* d_ws, size_t ws_size,
                              hipStream_t stream) {
  const float* x    = (const float*)d_in[0];
  const int*   xlen = (const int*)d_in[1];
  const float* I    = (const float*)d_in[2];
  const float* WQ0  = (const float*)d_in[3];
  const float* WK0  = (const float*)d_in[4];
  const float* WV0  = (const float*)d_in[5];
  const float* FCw0 = (const float*)d_in[6];
  const float* FCb0 = (const float*)d_in[7];
  const float* g00  = (const float*)d_in[8];
  const float* b00  = (const float*)d_in[9];
  const float* g01  = (const float*)d_in[10];
  const float* b01  = (const float*)d_in[11];
  const float* WQ1  = (const float*)d_in[12];
  const float* WK1  = (const float*)d_in[13];
  const float* WV1  = (const float*)d_in[14];
  const float* FCw1 = (const float*)d_in[15];
  const float* FCb1 = (const float*)d_in[16];
  const float* g10  = (const float*)d_in[17];
  const float* b10  = (const float*)d_in[18];
  const float* g11  = (const float*)d_in[19];
  const float* b11  = (const float*)d_in[20];

  char* p = (char*)d_ws;
  int* off = (int*)p;               p += 1024;
  ushort_t* QK0bf = (ushort_t*)p;   p += 64 * 64 * 2;
  ushort_t* Wfcbf = (ushort_t*)p;   p += 64 * 64 * 2;
  ushort_t* K1fbf = (ushort_t*)p;   p += (size_t)NB * 64 * 64 * 2;
  ushort_t* V1Tbf = (ushort_t*)p;   p += (size_t)NB * 64 * 64 * 2;
  float* pmx = (float*)p;           p += (size_t)NB * NCHUNK * 64 * 4;
  float* psm = (float*)p;           p += (size_t)NB * NCHUNK * 64 * 4;
  float* pax = (float*)p;           // NB*NCHUNK*64*64 floats = 8 MB

  k_setup<<<1, 256, 0, stream>>>(xlen, I, WQ0, WK0, FCw1, off, QK0bf, Wfcbf);
  k_phaseA<<<NB * NCHUNK, 256, 0, stream>>>(x, off, QK0bf, pmx, psm, pax);
  k_combine<<<NB, 256, 0, stream>>>(pmx, psm, pax, I, WV0, FCw0, FCb0,
                                    g00, b00, g01, b01, WK1, WQ1, WV1,
                                    K1fbf, V1Tbf);
  k_phaseB<<<NB * 64, 256, 0, stream>>>(x, off, K1fbf, V1Tbf, Wfcbf, FCb1,
                                        g10, b10, g11, b11, (float*)d_out);
}

// Round 3
// 145.545 us; speedup vs baseline: 5.0403x; 1.8408x over previous
//
#include <hip/hip_runtime.h>

#define NB 64
#define NCHUNK 8
#define ZINV 0.125f
#define EPS 1e-5f

typedef __attribute__((ext_vector_type(8))) short short8;
typedef __attribute__((ext_vector_type(4))) float f32x4;
typedef unsigned short ushort_t;

__device__ __forceinline__ f32x4 mm(short8 a, short8 b, f32x4 c) {
  return __builtin_amdgcn_mfma_f32_16x16x32_bf16(a, b, c, 0, 0, 0);
}
__device__ __forceinline__ ushort_t f2bf(float f) {
  unsigned u = __float_as_uint(f);
  u += 0x7fffu + ((u >> 16) & 1u);
  return (ushort_t)(u >> 16);
}
__device__ __forceinline__ unsigned pack2(float a, float b) {
  return (unsigned)f2bf(a) | ((unsigned)f2bf(b) << 16);
}
__device__ __forceinline__ float bf2f(ushort_t h) {
  return __uint_as_float(((unsigned)h) << 16);
}

// ---------------------------------------------------------------------------
// Setup: offsets; bf16 tables: QK0bf=(I WQ0^T WK0)/Z, Wfcbf=FCw1,
//        WV0bf, FCw0bf, WK1bf, WV1bf, WQ1Tbf (transposed)
// ---------------------------------------------------------------------------
__global__ __launch_bounds__(256) void k_setup(const int* __restrict__ xlens,
                                               const float* __restrict__ I,
                                               const float* __restrict__ WQ0,
                                               const float* __restrict__ WK0,
                                               const float* __restrict__ FCw1,
                                               const float* __restrict__ WV0,
                                               const float* __restrict__ FCw0,
                                               const float* __restrict__ WK1,
                                               const float* __restrict__ WQ1,
                                               const float* __restrict__ WV1,
                                               int* __restrict__ off,
                                               ushort_t* __restrict__ QK0bf,
                                               ushort_t* __restrict__ Wfcbf,
                                               ushort_t* __restrict__ WV0bf,
                                               ushort_t* __restrict__ FCw0bf,
                                               ushort_t* __restrict__ WK1bf,
                                               ushort_t* __restrict__ WQ1Tbf,
                                               ushort_t* __restrict__ WV1bf) {
  int tid = threadIdx.x;
  if (tid == 0) {
    int s = 0;
    off[0] = 0;
    for (int b = 0; b < NB; ++b) { s += xlens[b]; off[b + 1] = s; }
  }
  __shared__ float qq0[64][68];
  int m = tid >> 2, q = tid & 3, e0 = q << 4;
#pragma unroll
  for (int i = 0; i < 16; ++i) {
    int a = e0 + i;
    float acc = 0.f;
    for (int d = 0; d < 64; ++d) acc += I[m * 64 + d] * WQ0[a * 64 + d];
    qq0[m][a] = acc;
  }
  // row m written/read by same 4-lane group (same wave) -> no barrier
#pragma unroll
  for (int i = 0; i < 16; ++i) {
    int e = e0 + i;
    float acc = 0.f;
    for (int a = 0; a < 64; ++a) acc += qq0[m][a] * WK0[a * 64 + e];
    QK0bf[m * 64 + e] = f2bf(acc * ZINV);
  }
#pragma unroll
  for (int i = 0; i < 16; ++i) {
    int idx = m * 64 + e0 + i;
    Wfcbf[idx] = f2bf(FCw1[idx]);
    WV0bf[idx] = f2bf(WV0[idx]);
    FCw0bf[idx] = f2bf(FCw0[idx]);
    WK1bf[idx] = f2bf(WK1[idx]);
    WV1bf[idx] = f2bf(WV1[idx]);
    WQ1Tbf[(e0 + i) * 64 + m] = f2bf(WQ1[idx]);  // [e][a]
  }
}

// ---------------------------------------------------------------------------
// Phase A: per (segment, chunk) MFMA flash-attention partials.
// ---------------------------------------------------------------------------
__global__ __launch_bounds__(256) void k_phaseA(const float* __restrict__ x,
                                                const int* __restrict__ off,
                                                const ushort_t* __restrict__ QK0bf,
                                                float* __restrict__ part_mx,
                                                float* __restrict__ part_sm,
                                                float* __restrict__ part_ax) {
  int b = blockIdx.x / NCHUNK, chunk = blockIdx.x % NCHUNK;
  int s0 = off[b], L = off[b + 1] - s0;
  int clen = (L + NCHUNK - 1) / NCHUNK;
  int t0 = chunk * clen;
  int t1 = t0 + clen; if (t1 > L) t1 = L;

  __shared__ ushort_t xbf[64][72];
  __shared__ ushort_t xT[64][72];
  __shared__ ushort_t pbf[64][72];
  __shared__ float S[64][68];
  __shared__ float pm[4][64];
  __shared__ float ps[4][64];

  int tid = threadIdx.x;
  int w = tid >> 6, l = tid & 63, l15 = l & 15, lh = l >> 4;
  int srow = tid >> 2, sc0 = (tid & 3) << 4;

  short8 bq[4][2];
#pragma unroll
  for (int n = 0; n < 4; ++n)
#pragma unroll
    for (int kt = 0; kt < 2; ++kt)
      bq[n][kt] = *(const short8*)(QK0bf + ((16 * n + l15) << 6) + kt * 32 + lh * 8);

  float mx = -1e30f, sm = 0.f;
  f32x4 acc[4];
#pragma unroll
  for (int n = 0; n < 4; ++n) acc[n] = (f32x4){0.f, 0.f, 0.f, 0.f};

  for (int tt = t0; tt < t1; tt += 64) {
    __syncthreads();
    {
      int g = tt + srow;
      unsigned* dst = (unsigned*)&xbf[srow][sc0];
      if (g < t1) {
        const float4* src = (const float4*)(x + ((size_t)(s0 + g) << 6) + sc0);
        float4 A0 = src[0], A1 = src[1], A2 = src[2], A3 = src[3];
        float vv[16] = {A0.x, A0.y, A0.z, A0.w, A1.x, A1.y, A1.z, A1.w,
                        A2.x, A2.y, A2.z, A2.w, A3.x, A3.y, A3.z, A3.w};
        dst[0] = pack2(vv[0], vv[1]);   dst[1] = pack2(vv[2], vv[3]);
        dst[2] = pack2(vv[4], vv[5]);   dst[3] = pack2(vv[6], vv[7]);
        dst[4] = pack2(vv[8], vv[9]);   dst[5] = pack2(vv[10], vv[11]);
        dst[6] = pack2(vv[12], vv[13]); dst[7] = pack2(vv[14], vv[15]);
#pragma unroll
        for (int i = 0; i < 16; ++i) xT[sc0 + i][srow] = f2bf(vv[i]);
      } else {
#pragma unroll
        for (int i = 0; i < 8; ++i) dst[i] = 0u;
#pragma unroll
        for (int i = 0; i < 16; ++i) xT[sc0 + i][srow] = 0;
      }
    }
    short8 a0 = *(const short8*)&xbf[16 * w + l15][lh * 8];
    short8 a1 = *(const short8*)&xbf[16 * w + l15][32 + lh * 8];
    f32x4 c1[4];
#pragma unroll
    for (int n = 0; n < 4; ++n) {
      c1[n] = mm(a0, bq[n][0], (f32x4){0.f, 0.f, 0.f, 0.f});
      c1[n] = mm(a1, bq[n][1], c1[n]);
    }
#pragma unroll
    for (int n = 0; n < 4; ++n)
#pragma unroll
      for (int r = 0; r < 4; ++r) {
        int tl = 16 * w + 4 * lh + r;
        S[16 * n + l15][tl] = (tt + tl < t1) ? c1[n][r] : -1e30f;
      }
    float sv[16];
    float lmax = -1e30f;
#pragma unroll
    for (int i = 0; i < 16; ++i) { sv[i] = S[l][16 * w + i]; lmax = fmaxf(lmax, sv[i]); }
    pm[w][l] = lmax;
    __syncthreads();
    float tmax = fmaxf(fmaxf(pm[0][l], pm[1][l]), fmaxf(pm[2][l], pm[3][l]));
    float nm = fmaxf(mx, tmax);
    float f = __expf(mx - nm);
    mx = nm;
    float psum = 0.f;
    float pv[16];
#pragma unroll
    for (int i = 0; i < 16; ++i) { pv[i] = __expf(sv[i] - nm); psum += pv[i]; }
    {
      unsigned* prow = (unsigned*)&pbf[l][16 * w];
#pragma unroll
      for (int i = 0; i < 8; ++i) prow[i] = pack2(pv[2 * i], pv[2 * i + 1]);
    }
    ps[w][l] = psum;
    __syncthreads();
    sm = sm * f + ps[0][l] + ps[1][l] + ps[2][l] + ps[3][l];
    float fv[4];
#pragma unroll
    for (int r = 0; r < 4; ++r) fv[r] = __shfl(f, 16 * w + 4 * lh + r);
#pragma unroll
    for (int n = 0; n < 4; ++n)
#pragma unroll
      for (int r = 0; r < 4; ++r) acc[n][r] *= fv[r];
    short8 pa0 = *(const short8*)&pbf[16 * w + l15][lh * 8];
    short8 pa1 = *(const short8*)&pbf[16 * w + l15][32 + lh * 8];
#pragma unroll
    for (int n = 0; n < 4; ++n) {
      short8 bx0 = *(const short8*)&xT[16 * n + l15][lh * 8];
      short8 bx1 = *(const short8*)&xT[16 * n + l15][32 + lh * 8];
      acc[n] = mm(pa0, bx0, acc[n]);
      acc[n] = mm(pa1, bx1, acc[n]);
    }
  }
  int base = (b * NCHUNK + chunk) * 64;
  if (w == 0) { part_mx[base + l] = mx; part_sm[base + l] = sm; }
#pragma unroll
  for (int n = 0; n < 4; ++n)
#pragma unroll
    for (int r = 0; r < 4; ++r) {
      int m = 16 * w + 4 * lh + r;
      part_ax[((size_t)(base + m) << 6) + 16 * n + l15] = acc[n][r];
    }
}

// ---------------------------------------------------------------------------
// Combine (MFMA): merge partials -> 5 chained per-wave GEMMs -> K1fbf, V1Tbf
// GEMM1: AV = av @ WV0^T      GEMM2: U = hh @ FCw0^T
// GEMM3: tmp = iseg @ WK1^T   GEMM4: K1f = tmp @ WQ1 (via WQ1T) * ZINV
// GEMM5: V1 = iseg @ WV1^T  (stored transposed)
// ---------------------------------------------------------------------------
__global__ __launch_bounds__(256) void k_combine(const float* __restrict__ part_mx,
                                                 const float* __restrict__ part_sm,
                                                 const float* __restrict__ part_ax,
                                                 const float* __restrict__ I,
                                                 const ushort_t* __restrict__ WV0bf,
                                                 const ushort_t* __restrict__ FCw0bf,
                                                 const float* __restrict__ FCb0,
                                                 const float* __restrict__ g00,
                                                 const float* __restrict__ b00,
                                                 const float* __restrict__ g01,
                                                 const float* __restrict__ b01,
                                                 const ushort_t* __restrict__ WK1bf,
                                                 const ushort_t* __restrict__ WQ1Tbf,
                                                 const ushort_t* __restrict__ WV1bf,
                                                 ushort_t* __restrict__ K1fbf,
                                                 ushort_t* __restrict__ V1Tbf) {
  int b = blockIdx.x;
  int tid = threadIdx.x;
  int w = tid >> 6, l = tid & 63, l15 = l & 15, lh = l >> 4;

  __shared__ ushort_t av[64][72];  // merged attention.x -> later iseg
  __shared__ ushort_t sb[64][72];  // hh -> later tmp

  // ---- merge partials (fp32, vectorized) ----
  {
    int m = tid >> 2, dq = tid & 3, e0 = dq << 4;
    float Mx = -1e30f;
#pragma unroll
    for (int c = 0; c < NCHUNK; ++c)
      Mx = fmaxf(Mx, part_mx[(b * NCHUNK + c) * 64 + m]);
    float S = 0.f;
    float ax[16];
#pragma unroll
    for (int i = 0; i < 16; ++i) ax[i] = 0.f;
#pragma unroll
    for (int c = 0; c < NCHUNK; ++c) {
      int pb = (b * NCHUNK + c) * 64 + m;
      float f = __expf(part_mx[pb] - Mx);
      S += part_sm[pb] * f;
      const f32x4* pa = (const f32x4*)(part_ax + ((size_t)pb << 6) + e0);
#pragma unroll
      for (int qd = 0; qd < 4; ++qd) {
        f32x4 v = pa[qd];
#pragma unroll
        for (int j = 0; j < 4; ++j) ax[qd * 4 + j] += v[j] * f;
      }
    }
    float invS = 1.f / S;
    unsigned* dst = (unsigned*)&av[m][e0];
#pragma unroll
    for (int i = 0; i < 8; ++i)
      dst[i] = pack2(ax[2 * i] * invS, ax[2 * i + 1] * invS);
  }
  __syncthreads();

  // per-lane epilogue params for col = 16n + l15
  float p00[4], q00[4], p01[4], q01[4], fcb[4];
#pragma unroll
  for (int n = 0; n < 4; ++n) {
    int d = 16 * n + l15;
    p00[n] = g00[d]; q00[n] = b00[d];
    p01[n] = g01[d]; q01[n] = b01[d];
    fcb[n] = FCb0[d];
  }
  int row = 16 * w + 4 * lh;

  // ---- GEMM1: AV = av @ WV0^T ; h = AV + I ; LN -> hh -> sb ----
  short8 a0 = *(const short8*)&av[16 * w + l15][lh * 8];
  short8 a1 = *(const short8*)&av[16 * w + l15][32 + lh * 8];
  f32x4 c1[4];
#pragma unroll
  for (int n = 0; n < 4; ++n) {
    short8 b0 = *(const short8*)(WV0bf + ((16 * n + l15) << 6) + lh * 8);
    short8 b1 = *(const short8*)(WV0bf + ((16 * n + l15) << 6) + 32 + lh * 8);
    c1[n] = mm(a0, b0, (f32x4){0.f, 0.f, 0.f, 0.f});
    c1[n] = mm(a1, b1, c1[n]);
  }
  float hh[4][4];
#pragma unroll
  for (int r = 0; r < 4; ++r) {
    float h[4];
#pragma unroll
    for (int n = 0; n < 4; ++n)
      h[n] = c1[n][r] + I[(row + r) * 64 + 16 * n + l15];
    float s1 = h[0] + h[1] + h[2] + h[3];
    s1 += __shfl_xor(s1, 1); s1 += __shfl_xor(s1, 2);
    s1 += __shfl_xor(s1, 4); s1 += __shfl_xor(s1, 8);
    float mean = s1 * 0.015625f;
    float s2 = 0.f;
#pragma unroll
    for (int n = 0; n < 4; ++n) { float c = h[n] - mean; s2 += c * c; }
    s2 += __shfl_xor(s2, 1); s2 += __shfl_xor(s2, 2);
    s2 += __shfl_xor(s2, 4); s2 += __shfl_xor(s2, 8);
    float rs = rsqrtf(s2 * 0.015625f + EPS);
#pragma unroll
    for (int n = 0; n < 4; ++n) {
      hh[n][r] = (h[n] - mean) * rs * p00[n] + q00[n];
      sb[row + r][16 * n + l15] = f2bf(hh[n][r]);
    }
  }
  // ---- GEMM2: U = hh @ FCw0^T ; u = hh + relu(U + b) ; LN -> iseg -> av ----
  short8 h0 = *(const short8*)&sb[16 * w + l15][lh * 8];
  short8 h1 = *(const short8*)&sb[16 * w + l15][32 + lh * 8];
  f32x4 c2[4];
#pragma unroll
  for (int n = 0; n < 4; ++n) {
    short8 b0 = *(const short8*)(FCw0bf + ((16 * n + l15) << 6) + lh * 8);
    short8 b1 = *(const short8*)(FCw0bf + ((16 * n + l15) << 6) + 32 + lh * 8);
    c2[n] = mm(h0, b0, (f32x4){0.f, 0.f, 0.f, 0.f});
    c2[n] = mm(h1, b1, c2[n]);
  }
#pragma unroll
  for (int r = 0; r < 4; ++r) {
    float u[4];
#pragma unroll
    for (int n = 0; n < 4; ++n)
      u[n] = hh[n][r] + fmaxf(c2[n][r] + fcb[n], 0.f);
    float s1 = u[0] + u[1] + u[2] + u[3];
    s1 += __shfl_xor(s1, 1); s1 += __shfl_xor(s1, 2);
    s1 += __shfl_xor(s1, 4); s1 += __shfl_xor(s1, 8);
    float mean = s1 * 0.015625f;
    float s2 = 0.f;
#pragma unroll
    for (int n = 0; n < 4; ++n) { float c = u[n] - mean; s2 += c * c; }
    s2 += __shfl_xor(s2, 1); s2 += __shfl_xor(s2, 2);
    s2 += __shfl_xor(s2, 4); s2 += __shfl_xor(s2, 8);
    float rs = rsqrtf(s2 * 0.015625f + EPS);
#pragma unroll
    for (int n = 0; n < 4; ++n)
      av[row + r][16 * n + l15] = f2bf((u[n] - mean) * rs * p01[n] + q01[n]);
  }
  // ---- GEMM3: tmp = iseg @ WK1^T -> sb ----
  short8 i0 = *(const short8*)&av[16 * w + l15][lh * 8];
  short8 i1 = *(const short8*)&av[16 * w + l15][32 + lh * 8];
  f32x4 c3[4];
#pragma unroll
  for (int n = 0; n < 4; ++n) {
    short8 b0 = *(const short8*)(WK1bf + ((16 * n + l15) << 6) + lh * 8);
    short8 b1 = *(const short8*)(WK1bf + ((16 * n + l15) << 6) + 32 + lh * 8);
    c3[n] = mm(i0, b0, (f32x4){0.f, 0.f, 0.f, 0.f});
    c3[n] = mm(i1, b1, c3[n]);
  }
#pragma unroll
  for (int n = 0; n < 4; ++n)
#pragma unroll
    for (int r = 0; r < 4; ++r)
      sb[row + r][16 * n + l15] = f2bf(c3[n][r]);
  // ---- GEMM4: K1f = tmp @ WQ1 (B = WQ1T) * ZINV ----
  short8 t0 = *(const short8*)&sb[16 * w + l15][lh * 8];
  short8 t1 = *(const short8*)&sb[16 * w + l15][32 + lh * 8];
  f32x4 c4[4];
#pragma unroll
  for (int n = 0; n < 4; ++n) {
    short8 b0 = *(const short8*)(WQ1Tbf + ((16 * n + l15) << 6) + lh * 8);
    short8 b1 = *(const short8*)(WQ1Tbf + ((16 * n + l15) << 6) + 32 + lh * 8);
    c4[n] = mm(t0, b0, (f32x4){0.f, 0.f, 0.f, 0.f});
    c4[n] = mm(t1, b1, c4[n]);
  }
#pragma unroll
  for (int n = 0; n < 4; ++n)
#pragma unroll
    for (int r = 0; r < 4; ++r)
      K1fbf[((size_t)(b * 64 + row + r) << 6) + 16 * n + l15] = f2bf(c4[n][r] * ZINV);
  // ---- GEMM5: V1 = iseg @ WV1^T ; store transposed ----
  f32x4 c5[4];
#pragma unroll
  for (int n = 0; n < 4; ++n) {
    short8 b0 = *(const short8*)(WV1bf + ((16 * n + l15) << 6) + lh * 8);
    short8 b1 = *(const short8*)(WV1bf + ((16 * n + l15) << 6) + 32 + lh * 8);
    c5[n] = mm(i0, b0, (f32x4){0.f, 0.f, 0.f, 0.f});
    c5[n] = mm(i1, b1, c5[n]);
  }
#pragma unroll
  for (int n = 0; n < 4; ++n)
#pragma unroll
    for (int r = 0; r < 4; ++r)
      V1Tbf[((size_t)(b * 64 + 16 * n + l15) << 6) + row + r] = f2bf(c5[n][r]);
}

// ---------------------------------------------------------------------------
// Phase B: per 64-token tile, 3 chained per-wave MFMA GEMMs, zero barriers.
// ---------------------------------------------------------------------------
__global__ __launch_bounds__(256) void k_phaseB(const float* __restrict__ x,
                                                const int* __restrict__ off,
                                                const ushort_t* __restrict__ K1fbf,
                                                const ushort_t* __restrict__ V1Tbf,
                                                const ushort_t* __restrict__ Wfcbf,
                                                const float* __restrict__ FCb1,
                                                const float* __restrict__ g10,
                                                const float* __restrict__ b10,
                                                const float* __restrict__ g11,
                                                const float* __restrict__ b11,
                                                float* __restrict__ outp) {
  int b = blockIdx.x >> 6, tile = blockIdx.x & 63;
  int s0 = off[b], L = off[b + 1] - s0;
  int t0 = tile << 6;
  if (t0 >= L) return;
  int nt = L - t0; if (nt > 64) nt = 64;

  __shared__ ushort_t xbf[64][72];
  __shared__ ushort_t pbf[64][72];

  int tid = threadIdx.x;
  int w = tid >> 6, l = tid & 63, l15 = l & 15, lh = l >> 4;
  int srow = tid >> 2, sc0 = (tid & 3) << 4;

  {
    unsigned* dst = (unsigned*)&xbf[srow][sc0];
    if (srow < nt) {
      const float4* src = (const float4*)(x + ((size_t)(s0 + t0 + srow) << 6) + sc0);
      float4 A0 = src[0], A1 = src[1], A2 = src[2], A3 = src[3];
      dst[0] = pack2(A0.x, A0.y); dst[1] = pack2(A0.z, A0.w);
      dst[2] = pack2(A1.x, A1.y); dst[3] = pack2(A1.z, A1.w);
      dst[4] = pack2(A2.x, A2.y); dst[5] = pack2(A2.z, A2.w);
      dst[6] = pack2(A3.x, A3.y); dst[7] = pack2(A3.z, A3.w);
    } else {
#pragma unroll
      for (int i = 0; i < 8; ++i) dst[i] = 0u;
    }
  }
  float gg0[4], bb0[4], gg1[4], bb1[4], fb[4];
#pragma unroll
  for (int n = 0; n < 4; ++n) {
    int d = 16 * n + l15;
    gg0[n] = g10[d]; bb0[n] = b10[d];
    gg1[n] = g11[d]; bb1[n] = b11[d];
    fb[n] = FCb1[d];
  }
  short8 a0 = *(const short8*)&xbf[16 * w + l15][lh * 8];
  short8 a1 = *(const short8*)&xbf[16 * w + l15][32 + lh * 8];
  const ushort_t* Kb = K1fbf + ((size_t)b << 12);
  f32x4 c1[4];
#pragma unroll
  for (int n = 0; n < 4; ++n) {
    short8 bk0 = *(const short8*)(Kb + ((16 * n + l15) << 6) + lh * 8);
    short8 bk1 = *(const short8*)(Kb + ((16 * n + l15) << 6) + 32 + lh * 8);
    c1[n] = mm(a0, bk0, (f32x4){0.f, 0.f, 0.f, 0.f});
    c1[n] = mm(a1, bk1, c1[n]);
  }
  float inv[4];
#pragma unroll
  for (int r = 0; r < 4; ++r) {
    float mxr = fmaxf(fmaxf(c1[0][r], c1[1][r]), fmaxf(c1[2][r], c1[3][r]));
    mxr = fmaxf(mxr, __shfl_xor(mxr, 1));
    mxr = fmaxf(mxr, __shfl_xor(mxr, 2));
    mxr = fmaxf(mxr, __shfl_xor(mxr, 4));
    mxr = fmaxf(mxr, __shfl_xor(mxr, 8));
    float s = 0.f;
#pragma unroll
    for (int n = 0; n < 4; ++n) {
      float p = __expf(c1[n][r] - mxr);
      c1[n][r] = p;
      s += p;
    }
    s += __shfl_xor(s, 1);
    s += __shfl_xor(s, 2);
    s += __shfl_xor(s, 4);
    s += __shfl_xor(s, 8);
    inv[r] = 1.f / s;
  }
#pragma unroll
  for (int n = 0; n < 4; ++n)
#pragma unroll
    for (int r = 0; r < 4; ++r)
      pbf[16 * w + 4 * lh + r][16 * n + l15] = f2bf(c1[n][r]);
  short8 pa0 = *(const short8*)&pbf[16 * w + l15][lh * 8];
  short8 pa1 = *(const short8*)&pbf[16 * w + l15][32 + lh * 8];
  const ushort_t* Vb = V1Tbf + ((size_t)b << 12);
  f32x4 c2[4];
#pragma unroll
  for (int n = 0; n < 4; ++n) {
    short8 bv0 = *(const short8*)(Vb + ((16 * n + l15) << 6) + lh * 8);
    short8 bv1 = *(const short8*)(Vb + ((16 * n + l15) << 6) + 32 + lh * 8);
    c2[n] = mm(pa0, bv0, (f32x4){0.f, 0.f, 0.f, 0.f});
    c2[n] = mm(pa1, bv1, c2[n]);
  }
  float hh[4][4];
#pragma unroll
  for (int r = 0; r < 4; ++r) {
    int t = 16 * w + 4 * lh + r;
    float h[4];
#pragma unroll
    for (int n = 0; n < 4; ++n)
      h[n] = c2[n][r] * inv[r] + bf2f(xbf[t][16 * n + l15]);
    float s1 = h[0] + h[1] + h[2] + h[3];
    s1 += __shfl_xor(s1, 1); s1 += __shfl_xor(s1, 2);
    s1 += __shfl_xor(s1, 4); s1 += __shfl_xor(s1, 8);
    float mean = s1 * 0.015625f;
    float s2 = 0.f;
#pragma unroll
    for (int n = 0; n < 4; ++n) { float c = h[n] - mean; s2 += c * c; }
    s2 += __shfl_xor(s2, 1); s2 += __shfl_xor(s2, 2);
    s2 += __shfl_xor(s2, 4); s2 += __shfl_xor(s2, 8);
    float rs = rsqrtf(s2 * 0.015625f + EPS);
#pragma unroll
    for (int n = 0; n < 4; ++n) {
      hh[n][r] = (h[n] - mean) * rs * gg0[n] + bb0[n];
      pbf[t][16 * n + l15] = f2bf(hh[n][r]);
    }
  }
  short8 ha0 = *(const short8*)&pbf[16 * w + l15][lh * 8];
  short8 ha1 = *(const short8*)&pbf[16 * w + l15][32 + lh * 8];
  f32x4 c3[4];
#pragma unroll
  for (int n = 0; n < 4; ++n) {
    short8 bw0 = *(const short8*)(Wfcbf + ((16 * n + l15) << 6) + lh * 8);
    short8 bw1 = *(const short8*)(Wfcbf + ((16 * n + l15) << 6) + 32 + lh * 8);
    c3[n] = mm(ha0, bw0, (f32x4){0.f, 0.f, 0.f, 0.f});
    c3[n] = mm(ha1, bw1, c3[n]);
  }
#pragma unroll
  for (int r = 0; r < 4; ++r) {
    int t = 16 * w + 4 * lh + r;
    float u[4];
#pragma unroll
    for (int n = 0; n < 4; ++n)
      u[n] = hh[n][r] + fmaxf(c3[n][r] + fb[n], 0.f);
    float s1 = u[0] + u[1] + u[2] + u[3];
    s1 += __shfl_xor(s1, 1); s1 += __shfl_xor(s1, 2);
    s1 += __shfl_xor(s1, 4); s1 += __shfl_xor(s1, 8);
    float mean = s1 * 0.015625f;
    float s2 = 0.f;
#pragma unroll
    for (int n = 0; n < 4; ++n) { float c = u[n] - mean; s2 += c * c; }
    s2 += __shfl_xor(s2, 1); s2 += __shfl_xor(s2, 2);
    s2 += __shfl_xor(s2, 4); s2 += __shfl_xor(s2, 8);
    float rs = rsqrtf(s2 * 0.015625f + EPS);
    if (t < nt) {
#pragma unroll
      for (int n = 0; n < 4; ++n)
        outp[((size_t)(s0 + t0 + t) << 6) + 16 * n + l15] =
            (u[n] - mean) * rs * gg1[n] + bb1[n];
    }
  }
}

// ---------------------------------------------------------------------------

extern "C" void kernel_launch(void* const* d_in, const int* in_sizes, int n_in,
                              void* d_out, int out_size, void* d_ws, size_t ws_size,
                              hipStream_t stream) {
  const float* x    = (const float*)d_in[0];
  const int*   xlen = (const int*)d_in[1];
  const float* I    = (const float*)d_in[2];
  const float* WQ0  = (const float*)d_in[3];
  const float* WK0  = (const float*)d_in[4];
  const float* WV0  = (const float*)d_in[5];
  const float* FCw0 = (const float*)d_in[6];
  const float* FCb0 = (const float*)d_in[7];
  const float* g00  = (const float*)d_in[8];
  const float* b00  = (const float*)d_in[9];
  const float* g01  = (const float*)d_in[10];
  const float* b01  = (const float*)d_in[11];
  const float* WQ1  = (const float*)d_in[12];
  const float* WK1  = (const float*)d_in[13];
  const float* WV1  = (const float*)d_in[14];
  const float* FCw1 = (const float*)d_in[15];
  const float* FCb1 = (const float*)d_in[16];
  const float* g10  = (const float*)d_in[17];
  const float* b10  = (const float*)d_in[18];
  const float* g11  = (const float*)d_in[19];
  const float* b11  = (const float*)d_in[20];

  char* p = (char*)d_ws;
  int* off = (int*)p;                p += 1024;
  ushort_t* QK0bf = (ushort_t*)p;    p += 64 * 64 * 2;
  ushort_t* Wfcbf = (ushort_t*)p;    p += 64 * 64 * 2;
  ushort_t* WV0bf = (ushort_t*)p;    p += 64 * 64 * 2;
  ushort_t* FCw0bf = (ushort_t*)p;   p += 64 * 64 * 2;
  ushort_t* WK1bf = (ushort_t*)p;    p += 64 * 64 * 2;
  ushort_t* WQ1Tbf = (ushort_t*)p;   p += 64 * 64 * 2;
  ushort_t* WV1bf = (ushort_t*)p;    p += 64 * 64 * 2;
  ushort_t* K1fbf = (ushort_t*)p;    p += (size_t)NB * 64 * 64 * 2;
  ushort_t* V1Tbf = (ushort_t*)p;    p += (size_t)NB * 64 * 64 * 2;
  float* pmx = (float*)p;            p += (size_t)NB * NCHUNK * 64 * 4;
  float* psm = (float*)p;            p += (size_t)NB * NCHUNK * 64 * 4;
  float* pax = (float*)p;            // NB*NCHUNK*64*64 floats = 8 MB

  k_setup<<<1, 256, 0, stream>>>(xlen, I, WQ0, WK0, FCw1, WV0, FCw0, WK1, WQ1, WV1,
                                 off, QK0bf, Wfcbf, WV0bf, FCw0bf, WK1bf, WQ1Tbf, WV1bf);
  k_phaseA<<<NB * NCHUNK, 256, 0, stream>>>(x, off, QK0bf, pmx, psm, pax);
  k_combine<<<NB, 256, 0, stream>>>(pmx, psm, pax, I, WV0bf, FCw0bf, FCb0,
                                    g00, b00, g01, b01, WK1bf, WQ1Tbf, WV1bf,
                                    K1fbf, V1Tbf);
  k_phaseB<<<NB * 64, 256, 0, stream>>>(x, off, K1fbf, V1Tbf, Wfcbf, FCb1,
                                        g10, b10, g11, b11, (float*)d_out);
}

// Round 4
// 95.554 us; speedup vs baseline: 7.6772x; 1.5232x over previous
//
#include <hip/hip_runtime.h>

#define NB 64
#define NCHUNK 8
#define ZINV 0.125f
#define EPS 1e-5f

typedef __attribute__((ext_vector_type(8))) short short8;
typedef __attribute__((ext_vector_type(4))) float f32x4;
typedef unsigned short ushort_t;

__device__ __forceinline__ f32x4 mm(short8 a, short8 b, f32x4 c) {
  return __builtin_amdgcn_mfma_f32_16x16x32_bf16(a, b, c, 0, 0, 0);
}
__device__ __forceinline__ ushort_t f2bf(float f) {
  unsigned u = __float_as_uint(f);
  u += 0x7fffu + ((u >> 16) & 1u);
  return (ushort_t)(u >> 16);
}
__device__ __forceinline__ unsigned pack2(float a, float b) {
  return (unsigned)f2bf(a) | ((unsigned)f2bf(b) << 16);
}
__device__ __forceinline__ float bf2f(ushort_t h) {
  return __uint_as_float(((unsigned)h) << 16);
}
// convert 16 contiguous f32 -> 16 contiguous bf16 (both 16B-aligned)
__device__ __forceinline__ void cvt16(const float* __restrict__ src, ushort_t* dst) {
  const float4* s = (const float4*)src;
  unsigned* d = (unsigned*)dst;
  float4 A0 = s[0], A1 = s[1], A2 = s[2], A3 = s[3];
  d[0] = pack2(A0.x, A0.y); d[1] = pack2(A0.z, A0.w);
  d[2] = pack2(A1.x, A1.y); d[3] = pack2(A1.z, A1.w);
  d[4] = pack2(A2.x, A2.y); d[5] = pack2(A2.z, A2.w);
  d[6] = pack2(A3.x, A3.y); d[7] = pack2(A3.z, A3.w);
}

// ---------------------------------------------------------------------------
// Setup (1 block): offsets; bf16 weight tables; QK0 via 2 MFMA GEMMs.
// ---------------------------------------------------------------------------
__global__ __launch_bounds__(256) void k_setup(const int* __restrict__ xlens,
                                               const float* __restrict__ I,
                                               const float* __restrict__ WQ0,
                                               const float* __restrict__ WK0,
                                               const float* __restrict__ FCw1,
                                               const float* __restrict__ WV0,
                                               const float* __restrict__ FCw0,
                                               const float* __restrict__ WK1,
                                               const float* __restrict__ WQ1,
                                               const float* __restrict__ WV1,
                                               int* __restrict__ off,
                                               ushort_t* __restrict__ QK0bf,
                                               ushort_t* __restrict__ Wfcbf,
                                               ushort_t* __restrict__ WV0bf,
                                               ushort_t* __restrict__ FCw0bf,
                                               ushort_t* __restrict__ WK1bf,
                                               ushort_t* __restrict__ WQ1Tbf,
                                               ushort_t* __restrict__ WV1bf) {
  int tid = threadIdx.x;
  if (tid == 0) {
    int s = 0;
    off[0] = 0;
    for (int b = 0; b < NB; ++b) { s += xlens[b]; off[b + 1] = s; }
  }
  __shared__ ushort_t Ibf[64][72];
  __shared__ ushort_t Wq0[64][72];
  __shared__ ushort_t Wk0T[64][72];
  __shared__ ushort_t qqbf[64][72];

  int w = tid >> 6, l = tid & 63, l15 = l & 15, lh = l >> 4;
  int srow = tid >> 2, sc0 = (tid & 3) << 4;
  int so = srow * 64 + sc0;

  // stage MFMA inputs to LDS (bf16)
  cvt16(I + so, &Ibf[srow][sc0]);
  cvt16(WQ0 + so, &Wq0[srow][sc0]);
  {
    const float* s = WK0 + so;
#pragma unroll
    for (int i = 0; i < 16; ++i) Wk0T[sc0 + i][srow] = f2bf(s[i]);  // [e][a]
  }
  // straight global conversions (vectorized 16B stores)
  cvt16(FCw1 + so, Wfcbf + so);
  cvt16(WV0 + so, WV0bf + so);
  cvt16(FCw0 + so, FCw0bf + so);
  cvt16(WK1 + so, WK1bf + so);
  cvt16(WV1 + so, WV1bf + so);
  {
    const float* s = WQ1 + so;
#pragma unroll
    for (int i = 0; i < 16; ++i) WQ1Tbf[(sc0 + i) * 64 + srow] = f2bf(s[i]);  // [e][a]
  }
  __syncthreads();

  // GEMM A: qq[m][a] = sum_d I[m][d] WQ0[a][d]
  short8 ai0 = *(const short8*)&Ibf[16 * w + l15][lh * 8];
  short8 ai1 = *(const short8*)&Ibf[16 * w + l15][32 + lh * 8];
  f32x4 cA[4];
#pragma unroll
  for (int n = 0; n < 4; ++n) {
    short8 b0 = *(const short8*)&Wq0[16 * n + l15][lh * 8];
    short8 b1 = *(const short8*)&Wq0[16 * n + l15][32 + lh * 8];
    cA[n] = mm(ai0, b0, (f32x4){0.f, 0.f, 0.f, 0.f});
    cA[n] = mm(ai1, b1, cA[n]);
  }
#pragma unroll
  for (int n = 0; n < 4; ++n)
#pragma unroll
    for (int r = 0; r < 4; ++r)
      qqbf[16 * w + 4 * lh + r][16 * n + l15] = f2bf(cA[n][r]);  // own-wave rows

  // GEMM B: QK0[m][e] = (sum_a qq[m][a] Wk0T[e][a]) * ZINV
  short8 aq0 = *(const short8*)&qqbf[16 * w + l15][lh * 8];
  short8 aq1 = *(const short8*)&qqbf[16 * w + l15][32 + lh * 8];
  f32x4 cB[4];
#pragma unroll
  for (int n = 0; n < 4; ++n) {
    short8 b0 = *(const short8*)&Wk0T[16 * n + l15][lh * 8];
    short8 b1 = *(const short8*)&Wk0T[16 * n + l15][32 + lh * 8];
    cB[n] = mm(aq0, b0, (f32x4){0.f, 0.f, 0.f, 0.f});
    cB[n] = mm(aq1, b1, cB[n]);
  }
#pragma unroll
  for (int n = 0; n < 4; ++n)
#pragma unroll
    for (int r = 0; r < 4; ++r)
      QK0bf[(16 * w + 4 * lh + r) * 64 + 16 * n + l15] = f2bf(cB[n][r] * ZINV);
}

// ---------------------------------------------------------------------------
// Phase A: per (segment, chunk) MFMA flash-attention partials.
// GEMM1: C[m][t] = QK0[m] . x_t   (A=QK0 hoisted, B=x row-major)
// softmax fully in-register per m-row; GEMM2: acc[m][e] += P[m][t] x[t][e]
// ---------------------------------------------------------------------------
__global__ __launch_bounds__(256) void k_phaseA(const float* __restrict__ x,
                                                const int* __restrict__ off,
                                                const ushort_t* __restrict__ QK0bf,
                                                float* __restrict__ part_mx,
                                                float* __restrict__ part_sm,
                                                float* __restrict__ part_ax) {
  int b = blockIdx.x / NCHUNK, chunk = blockIdx.x % NCHUNK;
  int s0 = off[b], L = off[b + 1] - s0;
  int clen = (L + NCHUNK - 1) / NCHUNK;
  int t0 = chunk * clen;
  int t1 = t0 + clen; if (t1 > L) t1 = L;

  __shared__ ushort_t xbf[64][72];  // [t][e]
  __shared__ ushort_t xT[64][72];   // [e][t]
  __shared__ ushort_t pbf[64][72];  // [m][t]

  int tid = threadIdx.x;
  int w = tid >> 6, l = tid & 63, l15 = l & 15, lh = l >> 4;
  int srow = tid >> 2, sc0 = (tid & 3) << 4;

  // hoisted A-frags: QK0 rows 16w+l15 (constant across tiles)
  short8 aq0 = *(const short8*)(QK0bf + ((16 * w + l15) << 6) + lh * 8);
  short8 aq1 = *(const short8*)(QK0bf + ((16 * w + l15) << 6) + 32 + lh * 8);

  float mx[4], sm[4];
#pragma unroll
  for (int r = 0; r < 4; ++r) { mx[r] = -1e30f; sm[r] = 0.f; }
  f32x4 acc[4];
#pragma unroll
  for (int n = 0; n < 4; ++n) acc[n] = (f32x4){0.f, 0.f, 0.f, 0.f};

  for (int tt = t0; tt < t1; tt += 64) {
    __syncthreads();  // protect xbf/xT from previous iteration's readers
    {
      int g = tt + srow;
      unsigned* dst = (unsigned*)&xbf[srow][sc0];
      if (g < t1) {
        const float4* src = (const float4*)(x + ((size_t)(s0 + g) << 6) + sc0);
        float4 A0 = src[0], A1 = src[1], A2 = src[2], A3 = src[3];
        float vv[16] = {A0.x, A0.y, A0.z, A0.w, A1.x, A1.y, A1.z, A1.w,
                        A2.x, A2.y, A2.z, A2.w, A3.x, A3.y, A3.z, A3.w};
        dst[0] = pack2(vv[0], vv[1]);   dst[1] = pack2(vv[2], vv[3]);
        dst[2] = pack2(vv[4], vv[5]);   dst[3] = pack2(vv[6], vv[7]);
        dst[4] = pack2(vv[8], vv[9]);   dst[5] = pack2(vv[10], vv[11]);
        dst[6] = pack2(vv[12], vv[13]); dst[7] = pack2(vv[14], vv[15]);
#pragma unroll
        for (int i = 0; i < 16; ++i) xT[sc0 + i][srow] = f2bf(vv[i]);
      } else {
#pragma unroll
        for (int i = 0; i < 8; ++i) dst[i] = 0u;
#pragma unroll
        for (int i = 0; i < 16; ++i) xT[sc0 + i][srow] = 0;
      }
    }
    __syncthreads();

    // ---- GEMM1: C[m=16w+4lh+r][t=16n+l15] ----
    f32x4 c1[4];
#pragma unroll
    for (int n = 0; n < 4; ++n) {
      short8 bx0 = *(const short8*)&xbf[16 * n + l15][lh * 8];
      short8 bx1 = *(const short8*)&xbf[16 * n + l15][32 + lh * 8];
      c1[n] = mm(aq0, bx0, (f32x4){0.f, 0.f, 0.f, 0.f});
      c1[n] = mm(aq1, bx1, c1[n]);
    }
    bool val[4];
#pragma unroll
    for (int n = 0; n < 4; ++n) val[n] = (tt + 16 * n + l15) < t1;

    // ---- in-register online softmax per m-row ----
    float p[4][4];  // [n][r]
#pragma unroll
    for (int r = 0; r < 4; ++r) {
      float tmax = -1e30f;
#pragma unroll
      for (int n = 0; n < 4; ++n) tmax = fmaxf(tmax, val[n] ? c1[n][r] : -1e30f);
      tmax = fmaxf(tmax, __shfl_xor(tmax, 1));
      tmax = fmaxf(tmax, __shfl_xor(tmax, 2));
      tmax = fmaxf(tmax, __shfl_xor(tmax, 4));
      tmax = fmaxf(tmax, __shfl_xor(tmax, 8));
      float nm = fmaxf(mx[r], tmax);
      float f = __expf(mx[r] - nm);
      mx[r] = nm;
      float psum = 0.f;
#pragma unroll
      for (int n = 0; n < 4; ++n) {
        float pv = val[n] ? __expf(c1[n][r] - nm) : 0.f;
        p[n][r] = pv;
        psum += pv;
      }
      psum += __shfl_xor(psum, 1);
      psum += __shfl_xor(psum, 2);
      psum += __shfl_xor(psum, 4);
      psum += __shfl_xor(psum, 8);
      sm[r] = sm[r] * f + psum;
#pragma unroll
      for (int n = 0; n < 4; ++n) acc[n][r] *= f;
    }
    // ---- P -> LDS (own-wave rows; no barrier) ----
#pragma unroll
    for (int n = 0; n < 4; ++n)
#pragma unroll
      for (int r = 0; r < 4; ++r)
        pbf[16 * w + 4 * lh + r][16 * n + l15] = f2bf(p[n][r]);
    // ---- GEMM2: acc[m][e] += P[m][t] x[t][e] ----
    short8 pa0 = *(const short8*)&pbf[16 * w + l15][lh * 8];
    short8 pa1 = *(const short8*)&pbf[16 * w + l15][32 + lh * 8];
#pragma unroll
    for (int n = 0; n < 4; ++n) {
      short8 bt0 = *(const short8*)&xT[16 * n + l15][lh * 8];
      short8 bt1 = *(const short8*)&xT[16 * n + l15][32 + lh * 8];
      acc[n] = mm(pa0, bt0, acc[n]);
      acc[n] = mm(pa1, bt1, acc[n]);
    }
  }
  // ---- epilogue: partial state ----
  int base = (b * NCHUNK + chunk) * 64;
  if (l15 == 0) {
#pragma unroll
    for (int r = 0; r < 4; ++r) {
      int m = 16 * w + 4 * lh + r;
      part_mx[base + m] = mx[r];
      part_sm[base + m] = sm[r];
    }
  }
#pragma unroll
  for (int n = 0; n < 4; ++n)
#pragma unroll
    for (int r = 0; r < 4; ++r) {
      int m = 16 * w + 4 * lh + r;
      part_ax[((size_t)(base + m) << 6) + 16 * n + l15] = acc[n][r];
    }
}

// ---------------------------------------------------------------------------
// Combine (MFMA): merge partials -> 5 chained per-wave GEMMs -> K1fbf, V1Tbf
// ---------------------------------------------------------------------------
__global__ __launch_bounds__(256) void k_combine(const float* __restrict__ part_mx,
                                                 const float* __restrict__ part_sm,
                                                 const float* __restrict__ part_ax,
                                                 const float* __restrict__ I,
                                                 const ushort_t* __restrict__ WV0bf,
                                                 const ushort_t* __restrict__ FCw0bf,
                                                 const float* __restrict__ FCb0,
                                                 const float* __restrict__ g00,
                                                 const float* __restrict__ b00,
                                                 const float* __restrict__ g01,
                                                 const float* __restrict__ b01,
                                                 const ushort_t* __restrict__ WK1bf,
                                                 const ushort_t* __restrict__ WQ1Tbf,
                                                 const ushort_t* __restrict__ WV1bf,
                                                 ushort_t* __restrict__ K1fbf,
                                                 ushort_t* __restrict__ V1Tbf) {
  int b = blockIdx.x;
  int tid = threadIdx.x;
  int w = tid >> 6, l = tid & 63, l15 = l & 15, lh = l >> 4;

  __shared__ ushort_t av[64][72];  // merged attention.x -> later iseg
  __shared__ ushort_t sb[64][72];  // hh -> later tmp

  {
    int m = tid >> 2, dq = tid & 3, e0 = dq << 4;
    float Mx = -1e30f;
#pragma unroll
    for (int c = 0; c < NCHUNK; ++c)
      Mx = fmaxf(Mx, part_mx[(b * NCHUNK + c) * 64 + m]);
    float S = 0.f;
    float ax[16];
#pragma unroll
    for (int i = 0; i < 16; ++i) ax[i] = 0.f;
#pragma unroll
    for (int c = 0; c < NCHUNK; ++c) {
      int pb = (b * NCHUNK + c) * 64 + m;
      float f = __expf(part_mx[pb] - Mx);
      S += part_sm[pb] * f;
      const f32x4* pa = (const f32x4*)(part_ax + ((size_t)pb << 6) + e0);
#pragma unroll
      for (int qd = 0; qd < 4; ++qd) {
        f32x4 v = pa[qd];
#pragma unroll
        for (int j = 0; j < 4; ++j) ax[qd * 4 + j] += v[j] * f;
      }
    }
    float invS = 1.f / S;
    unsigned* dst = (unsigned*)&av[m][e0];
#pragma unroll
    for (int i = 0; i < 8; ++i)
      dst[i] = pack2(ax[2 * i] * invS, ax[2 * i + 1] * invS);
  }
  __syncthreads();

  float p00[4], q00[4], p01[4], q01[4], fcb[4];
#pragma unroll
  for (int n = 0; n < 4; ++n) {
    int d = 16 * n + l15;
    p00[n] = g00[d]; q00[n] = b00[d];
    p01[n] = g01[d]; q01[n] = b01[d];
    fcb[n] = FCb0[d];
  }
  int row = 16 * w + 4 * lh;

  short8 a0 = *(const short8*)&av[16 * w + l15][lh * 8];
  short8 a1 = *(const short8*)&av[16 * w + l15][32 + lh * 8];
  f32x4 c1[4];
#pragma unroll
  for (int n = 0; n < 4; ++n) {
    short8 b0 = *(const short8*)(WV0bf + ((16 * n + l15) << 6) + lh * 8);
    short8 b1 = *(const short8*)(WV0bf + ((16 * n + l15) << 6) + 32 + lh * 8);
    c1[n] = mm(a0, b0, (f32x4){0.f, 0.f, 0.f, 0.f});
    c1[n] = mm(a1, b1, c1[n]);
  }
  float hh[4][4];
#pragma unroll
  for (int r = 0; r < 4; ++r) {
    float h[4];
#pragma unroll
    for (int n = 0; n < 4; ++n)
      h[n] = c1[n][r] + I[(row + r) * 64 + 16 * n + l15];
    float s1 = h[0] + h[1] + h[2] + h[3];
    s1 += __shfl_xor(s1, 1); s1 += __shfl_xor(s1, 2);
    s1 += __shfl_xor(s1, 4); s1 += __shfl_xor(s1, 8);
    float mean = s1 * 0.015625f;
    float s2 = 0.f;
#pragma unroll
    for (int n = 0; n < 4; ++n) { float c = h[n] - mean; s2 += c * c; }
    s2 += __shfl_xor(s2, 1); s2 += __shfl_xor(s2, 2);
    s2 += __shfl_xor(s2, 4); s2 += __shfl_xor(s2, 8);
    float rs = rsqrtf(s2 * 0.015625f + EPS);
#pragma unroll
    for (int n = 0; n < 4; ++n) {
      hh[n][r] = (h[n] - mean) * rs * p00[n] + q00[n];
      sb[row + r][16 * n + l15] = f2bf(hh[n][r]);
    }
  }
  short8 h0 = *(const short8*)&sb[16 * w + l15][lh * 8];
  short8 h1 = *(const short8*)&sb[16 * w + l15][32 + lh * 8];
  f32x4 c2[4];
#pragma unroll
  for (int n = 0; n < 4; ++n) {
    short8 b0 = *(const short8*)(FCw0bf + ((16 * n + l15) << 6) + lh * 8);
    short8 b1 = *(const short8*)(FCw0bf + ((16 * n + l15) << 6) + 32 + lh * 8);
    c2[n] = mm(h0, b0, (f32x4){0.f, 0.f, 0.f, 0.f});
    c2[n] = mm(h1, b1, c2[n]);
  }
#pragma unroll
  for (int r = 0; r < 4; ++r) {
    float u[4];
#pragma unroll
    for (int n = 0; n < 4; ++n)
      u[n] = hh[n][r] + fmaxf(c2[n][r] + fcb[n], 0.f);
    float s1 = u[0] + u[1] + u[2] + u[3];
    s1 += __shfl_xor(s1, 1); s1 += __shfl_xor(s1, 2);
    s1 += __shfl_xor(s1, 4); s1 += __shfl_xor(s1, 8);
    float mean = s1 * 0.015625f;
    float s2 = 0.f;
#pragma unroll
    for (int n = 0; n < 4; ++n) { float c = u[n] - mean; s2 += c * c; }
    s2 += __shfl_xor(s2, 1); s2 += __shfl_xor(s2, 2);
    s2 += __shfl_xor(s2, 4); s2 += __shfl_xor(s2, 8);
    float rs = rsqrtf(s2 * 0.015625f + EPS);
#pragma unroll
    for (int n = 0; n < 4; ++n)
      av[row + r][16 * n + l15] = f2bf((u[n] - mean) * rs * p01[n] + q01[n]);
  }
  short8 i0 = *(const short8*)&av[16 * w + l15][lh * 8];
  short8 i1 = *(const short8*)&av[16 * w + l15][32 + lh * 8];
  f32x4 c3[4];
#pragma unroll
  for (int n = 0; n < 4; ++n) {
    short8 b0 = *(const short8*)(WK1bf + ((16 * n + l15) << 6) + lh * 8);
    short8 b1 = *(const short8*)(WK1bf + ((16 * n + l15) << 6) + 32 + lh * 8);
    c3[n] = mm(i0, b0, (f32x4){0.f, 0.f, 0.f, 0.f});
    c3[n] = mm(i1, b1, c3[n]);
  }
#pragma unroll
  for (int n = 0; n < 4; ++n)
#pragma unroll
    for (int r = 0; r < 4; ++r)
      sb[row + r][16 * n + l15] = f2bf(c3[n][r]);
  short8 t0 = *(const short8*)&sb[16 * w + l15][lh * 8];
  short8 t1 = *(const short8*)&sb[16 * w + l15][32 + lh * 8];
  f32x4 c4[4];
#pragma unroll
  for (int n = 0; n < 4; ++n) {
    short8 b0 = *(const short8*)(WQ1Tbf + ((16 * n + l15) << 6) + lh * 8);
    short8 b1 = *(const short8*)(WQ1Tbf + ((16 * n + l15) << 6) + 32 + lh * 8);
    c4[n] = mm(t0, b0, (f32x4){0.f, 0.f, 0.f, 0.f});
    c4[n] = mm(t1, b1, c4[n]);
  }
#pragma unroll
  for (int n = 0; n < 4; ++n)
#pragma unroll
    for (int r = 0; r < 4; ++r)
      K1fbf[((size_t)(b * 64 + row + r) << 6) + 16 * n + l15] = f2bf(c4[n][r] * ZINV);
  f32x4 c5[4];
#pragma unroll
  for (int n = 0; n < 4; ++n) {
    short8 b0 = *(const short8*)(WV1bf + ((16 * n + l15) << 6) + lh * 8);
    short8 b1 = *(const short8*)(WV1bf + ((16 * n + l15) << 6) + 32 + lh * 8);
    c5[n] = mm(i0, b0, (f32x4){0.f, 0.f, 0.f, 0.f});
    c5[n] = mm(i1, b1, c5[n]);
  }
#pragma unroll
  for (int n = 0; n < 4; ++n)
#pragma unroll
    for (int r = 0; r < 4; ++r)
      V1Tbf[((size_t)(b * 64 + 16 * n + l15) << 6) + row + r] = f2bf(c5[n][r]);
}

// ---------------------------------------------------------------------------
// Phase B: per 64-token tile, 3 chained per-wave MFMA GEMMs, zero barriers.
// ---------------------------------------------------------------------------
__global__ __launch_bounds__(256) void k_phaseB(const float* __restrict__ x,
                                                const int* __restrict__ off,
                                                const ushort_t* __restrict__ K1fbf,
                                                const ushort_t* __restrict__ V1Tbf,
                                                const ushort_t* __restrict__ Wfcbf,
                                                const float* __restrict__ FCb1,
                                                const float* __restrict__ g10,
                                                const float* __restrict__ b10,
                                                const float* __restrict__ g11,
                                                const float* __restrict__ b11,
                                                float* __restrict__ outp) {
  int b = blockIdx.x >> 6, tile = blockIdx.x & 63;
  int s0 = off[b], L = off[b + 1] - s0;
  int t0 = tile << 6;
  if (t0 >= L) return;
  int nt = L - t0; if (nt > 64) nt = 64;

  __shared__ ushort_t xbf[64][72];
  __shared__ ushort_t pbf[64][72];

  int tid = threadIdx.x;
  int w = tid >> 6, l = tid & 63, l15 = l & 15, lh = l >> 4;
  int srow = tid >> 2, sc0 = (tid & 3) << 4;

  {
    unsigned* dst = (unsigned*)&xbf[srow][sc0];
    if (srow < nt) {
      const float4* src = (const float4*)(x + ((size_t)(s0 + t0 + srow) << 6) + sc0);
      float4 A0 = src[0], A1 = src[1], A2 = src[2], A3 = src[3];
      dst[0] = pack2(A0.x, A0.y); dst[1] = pack2(A0.z, A0.w);
      dst[2] = pack2(A1.x, A1.y); dst[3] = pack2(A1.z, A1.w);
      dst[4] = pack2(A2.x, A2.y); dst[5] = pack2(A2.z, A2.w);
      dst[6] = pack2(A3.x, A3.y); dst[7] = pack2(A3.z, A3.w);
    } else {
#pragma unroll
      for (int i = 0; i < 8; ++i) dst[i] = 0u;
    }
  }
  float gg0[4], bb0[4], gg1[4], bb1[4], fb[4];
#pragma unroll
  for (int n = 0; n < 4; ++n) {
    int d = 16 * n + l15;
    gg0[n] = g10[d]; bb0[n] = b10[d];
    gg1[n] = g11[d]; bb1[n] = b11[d];
    fb[n] = FCb1[d];
  }
  short8 a0 = *(const short8*)&xbf[16 * w + l15][lh * 8];
  short8 a1 = *(const short8*)&xbf[16 * w + l15][32 + lh * 8];
  const ushort_t* Kb = K1fbf + ((size_t)b << 12);
  f32x4 c1[4];
#pragma unroll
  for (int n = 0; n < 4; ++n) {
    short8 bk0 = *(const short8*)(Kb + ((16 * n + l15) << 6) + lh * 8);
    short8 bk1 = *(const short8*)(Kb + ((16 * n + l15) << 6) + 32 + lh * 8);
    c1[n] = mm(a0, bk0, (f32x4){0.f, 0.f, 0.f, 0.f});
    c1[n] = mm(a1, bk1, c1[n]);
  }
  float inv[4];
#pragma unroll
  for (int r = 0; r < 4; ++r) {
    float mxr = fmaxf(fmaxf(c1[0][r], c1[1][r]), fmaxf(c1[2][r], c1[3][r]));
    mxr = fmaxf(mxr, __shfl_xor(mxr, 1));
    mxr = fmaxf(mxr, __shfl_xor(mxr, 2));
    mxr = fmaxf(mxr, __shfl_xor(mxr, 4));
    mxr = fmaxf(mxr, __shfl_xor(mxr, 8));
    float s = 0.f;
#pragma unroll
    for (int n = 0; n < 4; ++n) {
      float p = __expf(c1[n][r] - mxr);
      c1[n][r] = p;
      s += p;
    }
    s += __shfl_xor(s, 1);
    s += __shfl_xor(s, 2);
    s += __shfl_xor(s, 4);
    s += __shfl_xor(s, 8);
    inv[r] = 1.f / s;
  }
#pragma unroll
  for (int n = 0; n < 4; ++n)
#pragma unroll
    for (int r = 0; r < 4; ++r)
      pbf[16 * w + 4 * lh + r][16 * n + l15] = f2bf(c1[n][r]);
  short8 pa0 = *(const short8*)&pbf[16 * w + l15][lh * 8];
  short8 pa1 = *(const short8*)&pbf[16 * w + l15][32 + lh * 8];
  const ushort_t* Vb = V1Tbf + ((size_t)b << 12);
  f32x4 c2[4];
#pragma unroll
  for (int n = 0; n < 4; ++n) {
    short8 bv0 = *(const short8*)(Vb + ((16 * n + l15) << 6) + lh * 8);
    short8 bv1 = *(const short8*)(Vb + ((16 * n + l15) << 6) + 32 + lh * 8);
    c2[n] = mm(pa0, bv0, (f32x4){0.f, 0.f, 0.f, 0.f});
    c2[n] = mm(pa1, bv1, c2[n]);
  }
  float hh[4][4];
#pragma unroll
  for (int r = 0; r < 4; ++r) {
    int t = 16 * w + 4 * lh + r;
    float h[4];
#pragma unroll
    for (int n = 0; n < 4; ++n)
      h[n] = c2[n][r] * inv[r] + bf2f(xbf[t][16 * n + l15]);
    float s1 = h[0] + h[1] + h[2] + h[3];
    s1 += __shfl_xor(s1, 1); s1 += __shfl_xor(s1, 2);
    s1 += __shfl_xor(s1, 4); s1 += __shfl_xor(s1, 8);
    float mean = s1 * 0.015625f;
    float s2 = 0.f;
#pragma unroll
    for (int n = 0; n < 4; ++n) { float c = h[n] - mean; s2 += c * c; }
    s2 += __shfl_xor(s2, 1); s2 += __shfl_xor(s2, 2);
    s2 += __shfl_xor(s2, 4); s2 += __shfl_xor(s2, 8);
    float rs = rsqrtf(s2 * 0.015625f + EPS);
#pragma unroll
    for (int n = 0; n < 4; ++n) {
      hh[n][r] = (h[n] - mean) * rs * gg0[n] + bb0[n];
      pbf[t][16 * n + l15] = f2bf(hh[n][r]);
    }
  }
  short8 ha0 = *(const short8*)&pbf[16 * w + l15][lh * 8];
  short8 ha1 = *(const short8*)&pbf[16 * w + l15][32 + lh * 8];
  f32x4 c3[4];
#pragma unroll
  for (int n = 0; n < 4; ++n) {
    short8 bw0 = *(const short8*)(Wfcbf + ((16 * n + l15) << 6) + lh * 8);
    short8 bw1 = *(const short8*)(Wfcbf + ((16 * n + l15) << 6) + 32 + lh * 8);
    c3[n] = mm(ha0, bw0, (f32x4){0.f, 0.f, 0.f, 0.f});
    c3[n] = mm(ha1, bw1, c3[n]);
  }
#pragma unroll
  for (int r = 0; r < 4; ++r) {
    int t = 16 * w + 4 * lh + r;
    float u[4];
#pragma unroll
    for (int n = 0; n < 4; ++n)
      u[n] = hh[n][r] + fmaxf(c3[n][r] + fb[n], 0.f);
    float s1 = u[0] + u[1] + u[2] + u[3];
    s1 += __shfl_xor(s1, 1); s1 += __shfl_xor(s1, 2);
    s1 += __shfl_xor(s1, 4); s1 += __shfl_xor(s1, 8);
    float mean = s1 * 0.015625f;
    float s2 = 0.f;
#pragma unroll
    for (int n = 0; n < 4; ++n) { float c = u[n] - mean; s2 += c * c; }
    s2 += __shfl_xor(s2, 1); s2 += __shfl_xor(s2, 2);
    s2 += __shfl_xor(s2, 4); s2 += __shfl_xor(s2, 8);
    float rs = rsqrtf(s2 * 0.015625f + EPS);
    if (t < nt) {
#pragma unroll
      for (int n = 0; n < 4; ++n)
        outp[((size_t)(s0 + t0 + t) << 6) + 16 * n + l15] =
            (u[n] - mean) * rs * gg1[n] + bb1[n];
    }
  }
}

// ---------------------------------------------------------------------------

extern "C" void kernel_launch(void* const* d_in, const int* in_sizes, int n_in,
                              void* d_out, int out_size, void* d_ws, size_t ws_size,
                              hipStream_t stream) {
  const float* x    = (const float*)d_in[0];
  const int*   xlen = (const int*)d_in[1];
  const float* I    = (const float*)d_in[2];
  const float* WQ0  = (const float*)d_in[3];
  const float* WK0  = (const float*)d_in[4];
  const float* WV0  = (const float*)d_in[5];
  const float* FCw0 = (const float*)d_in[6];
  const float* FCb0 = (const float*)d_in[7];
  const float* g00  = (const float*)d_in[8];
  const float* b00  = (const float*)d_in[9];
  const float* g01  = (const float*)d_in[10];
  const float* b01  = (const float*)d_in[11];
  const float* WQ1  = (const float*)d_in[12];
  const float* WK1  = (const float*)d_in[13];
  const float* WV1  = (const float*)d_in[14];
  const float* FCw1 = (const float*)d_in[15];
  const float* FCb1 = (const float*)d_in[16];
  const float* g10  = (const float*)d_in[17];
  const float* b10  = (const float*)d_in[18];
  const float* g11  = (const float*)d_in[19];
  const float* b11  = (const float*)d_in[20];

  char* p = (char*)d_ws;
  int* off = (int*)p;                p += 1024;
  ushort_t* QK0bf = (ushort_t*)p;    p += 64 * 64 * 2;
  ushort_t* Wfcbf = (ushort_t*)p;    p += 64 * 64 * 2;
  ushort_t* WV0bf = (ushort_t*)p;    p += 64 * 64 * 2;
  ushort_t* FCw0bf = (ushort_t*)p;   p += 64 * 64 * 2;
  ushort_t* WK1bf = (ushort_t*)p;    p += 64 * 64 * 2;
  ushort_t* WQ1Tbf = (ushort_t*)p;   p += 64 * 64 * 2;
  ushort_t* WV1bf = (ushort_t*)p;    p += 64 * 64 * 2;
  ushort_t* K1fbf = (ushort_t*)p;    p += (size_t)NB * 64 * 64 * 2;
  ushort_t* V1Tbf = (ushort_t*)p;    p += (size_t)NB * 64 * 64 * 2;
  float* pmx = (float*)p;            p += (size_t)NB * NCHUNK * 64 * 4;
  float* psm = (float*)p;            p += (size_t)NB * NCHUNK * 64 * 4;
  float* pax = (float*)p;            // NB*NCHUNK*64*64 floats = 8 MB

  k_setup<<<1, 256, 0, stream>>>(xlen, I, WQ0, WK0, FCw1, WV0, FCw0, WK1, WQ1, WV1,
                                 off, QK0bf, Wfcbf, WV0bf, FCw0bf, WK1bf, WQ1Tbf, WV1bf);
  k_phaseA<<<NB * NCHUNK, 256, 0, stream>>>(x, off, QK0bf, pmx, psm, pax);
  k_combine<<<NB, 256, 0, stream>>>(pmx, psm, pax, I, WV0bf, FCw0bf, FCb0,
                                    g00, b00, g01, b01, WK1bf, WQ1Tbf, WV1bf,
                                    K1fbf, V1Tbf);
  k_phaseB<<<NB * 64, 256, 0, stream>>>(x, off, K1fbf, V1Tbf, Wfcbf, FCb1,
                                        g10, b10, g11, b11, (float*)d_out);
}